// Round 1
// baseline (1069.202 us; speedup 1.0000x reference)
//
#include <hip/hip_runtime.h>
#include <math.h>

#define T_DIM  4096
#define REPR_D 2048
#define FEAT_D 1024
#define HID_D  1024
#define GATE_D 256
#define MH_D   256
#define NE     32
#define TOPK   4
#define ACT_D  12
#define LN_EPS 1e-5f

// ---------------- generic tiled f32 GEMM: C = act(A[M,K] @ B[K,N] + bias) --------------
template<bool RELU>
__global__ __launch_bounds__(256)
void gemm_bias_act(const float* __restrict__ A, const float* __restrict__ B,
                   const float* __restrict__ bias, float* __restrict__ C,
                   int M, int N, int K) {
  __shared__ float As[16][64];
  __shared__ float Bs[16][64];
  const int tid = threadIdx.x;
  const int bm = blockIdx.y * 64;
  const int bn = blockIdx.x * 64;
  const int tx = tid & 15, ty = tid >> 4;
  float acc[4][4] = {};
  for (int k0 = 0; k0 < K; k0 += 16) {
    {
      const int r = tid >> 2, c = (tid & 3) << 2;
      float4 a = *(const float4*)(A + (size_t)(bm + r) * K + (k0 + c));
      As[c + 0][r] = a.x; As[c + 1][r] = a.y; As[c + 2][r] = a.z; As[c + 3][r] = a.w;
      const int rb = tid >> 4, cb = (tid & 15) << 2;
      *(float4*)(&Bs[rb][cb]) = *(const float4*)(B + (size_t)(k0 + rb) * N + (bn + cb));
    }
    __syncthreads();
    #pragma unroll
    for (int kk = 0; kk < 16; ++kk) {
      const float4 a4 = *(const float4*)(&As[kk][ty << 2]);
      const float4 b4 = *(const float4*)(&Bs[kk][tx << 2]);
      const float av[4] = {a4.x, a4.y, a4.z, a4.w};
      const float bv[4] = {b4.x, b4.y, b4.z, b4.w};
      #pragma unroll
      for (int i = 0; i < 4; ++i)
        #pragma unroll
        for (int j = 0; j < 4; ++j)
          acc[i][j] = fmaf(av[i], bv[j], acc[i][j]);
    }
    __syncthreads();
  }
  #pragma unroll
  for (int i = 0; i < 4; ++i) {
    const int row = bm + (ty << 2) + i;
    #pragma unroll
    for (int j = 0; j < 4; ++j) {
      const int col = bn + (tx << 2) + j;
      float v = acc[i][j] + bias[col];
      if (RELU) v = fmaxf(v, 0.f);
      C[(size_t)row * N + col] = v;
    }
  }
}

// ---------------- LayerNorm + tanh, in place, one block per row (FEAT_D) ----------------
__global__ __launch_bounds__(256)
void ln_tanh(float* __restrict__ h, const float* __restrict__ g, const float* __restrict__ b) {
  const int row = blockIdx.x;
  float* x = h + (size_t)row * FEAT_D;
  float s = 0.f, ss = 0.f;
  for (int i = threadIdx.x; i < FEAT_D; i += 256) {
    float v = x[i]; s += v; ss += v * v;
  }
  #pragma unroll
  for (int d = 32; d >= 1; d >>= 1) { s += __shfl_xor(s, d, 64); ss += __shfl_xor(ss, d, 64); }
  __shared__ float red[2][4];
  const int w = threadIdx.x >> 6;
  if ((threadIdx.x & 63) == 0) { red[0][w] = s; red[1][w] = ss; }
  __syncthreads();
  s  = red[0][0] + red[0][1] + red[0][2] + red[0][3];
  ss = red[1][0] + red[1][1] + red[1][2] + red[1][3];
  const float m = s * (1.f / FEAT_D);
  const float var = ss * (1.f / FEAT_D) - m * m;
  const float inv = rsqrtf(var + LN_EPS);
  for (int i = threadIdx.x; i < FEAT_D; i += 256)
    x[i] = tanhf((x[i] - m) * inv * g[i] + b[i]);
}

// ------------- gate layer 2 + softmax + top-4 + renorm + aux accumulation --------------
// block = 256 threads = 8 tokens x 32 experts
__global__ __launch_bounds__(256)
void gate2_topk(const float* __restrict__ hg, const float* __restrict__ g2w,
                const float* __restrict__ g2b, float* __restrict__ imp,
                int* __restrict__ counts, int* __restrict__ topi, float* __restrict__ topw) {
  __shared__ float wsm[GATE_D][NE];   // 32 KB
  __shared__ float rows[8][GATE_D];   // 8 KB
  __shared__ float pacc[8][NE];       // 1 KB
  const int tid = threadIdx.x;
  const int t0 = blockIdx.x * 8;
  for (int i = tid; i < GATE_D * NE; i += 256) wsm[i / NE][i % NE] = g2w[i];
  for (int i = tid; i < 8 * GATE_D; i += 256)
    rows[i / GATE_D][i % GATE_D] = hg[(size_t)(t0 + i / GATE_D) * GATE_D + (i % GATE_D)];
  __syncthreads();
  const int tl = tid >> 5;       // token within block
  const int e  = tid & 31;       // expert lane
  const int t  = t0 + tl;
  float logit = g2b[e];
  for (int k = 0; k < GATE_D; ++k) logit = fmaf(rows[tl][k], wsm[k][e], logit);
  // softmax over the 32 lanes of this token
  float m = logit;
  #pragma unroll
  for (int d = 16; d >= 1; d >>= 1) m = fmaxf(m, __shfl_xor(m, d, 32));
  const float p = expf(logit - m);
  float ssum = p;
  #pragma unroll
  for (int d = 16; d >= 1; d >>= 1) ssum += __shfl_xor(ssum, d, 32);
  const float prob = p / ssum;
  // importance accumulation (pre-reduce 8 tokens in LDS -> 1 atomic per expert per block)
  pacc[tl][e] = prob;
  __syncthreads();
  if (tl == 0) {
    float a = 0.f;
    #pragma unroll
    for (int q = 0; q < 8; ++q) a += pacc[q][e];
    atomicAdd(&imp[e], a);
  }
  // top-4 with tie-break to lower index (matches lax.top_k)
  float cur = prob;
  float wv[TOPK]; int wi[TOPK];
  #pragma unroll
  for (int it = 0; it < TOPK; ++it) {
    float v = cur; int idx = e;
    #pragma unroll
    for (int d = 16; d >= 1; d >>= 1) {
      float v2 = __shfl_xor(v, d, 32);
      int   i2 = __shfl_xor(idx, d, 32);
      if (v2 > v || (v2 == v && i2 < idx)) { v = v2; idx = i2; }
    }
    wv[it] = v; wi[it] = idx;
    if (e == idx) cur = -1e30f;
  }
  if (e == 0) {
    const float s4 = wv[0] + wv[1] + wv[2] + wv[3];
    #pragma unroll
    for (int k2 = 0; k2 < TOPK; ++k2) {
      topi[t * TOPK + k2] = wi[k2];
      topw[t * TOPK + k2] = wv[k2] / s4;
      atomicAdd(&counts[wi[k2]], 1);
    }
  }
}

__global__ void scan_offsets(const int* __restrict__ counts, int* __restrict__ offsets) {
  if (threadIdx.x == 0) {
    int a = 0;
    for (int e = 0; e < NE; ++e) { offsets[e] = a; a += counts[e]; }
    offsets[NE] = a;
  }
}

__global__ __launch_bounds__(256)
void fill_perm(const int* __restrict__ topi, const int* __restrict__ offsets,
               int* __restrict__ fill, int* __restrict__ perm) {
  const int s = blockIdx.x * 256 + threadIdx.x;     // slot id = t*TOPK + k
  const int e = topi[s];
  const int pos = atomicAdd(&fill[e], 1);
  perm[offsets[e] + pos] = s;
}

// ------------- expert layer 1 (gathered rows of x): h = relu(x[t] @ ew1[e] + eb1[e]) ----
__global__ __launch_bounds__(256)
void expert_l1(const float* __restrict__ x, const float* __restrict__ ew1,
               const float* __restrict__ eb1, const int* __restrict__ perm,
               const int* __restrict__ offsets, const int* __restrict__ counts,
               float* __restrict__ hbuf) {
  const int e = blockIdx.z;
  const int cnt = counts[e];
  const int r0 = blockIdx.y * 64;
  if (r0 >= cnt) return;
  const int bn = blockIdx.x * 64;
  const float* B = ew1 + (size_t)e * HID_D * MH_D;
  const int base = offsets[e];
  __shared__ float As[16][64];
  __shared__ float Bs[16][64];
  __shared__ int toks[64];
  const int tid = threadIdx.x;
  if (tid < 64) {
    const int r = r0 + tid;
    toks[tid] = (r < cnt) ? (perm[base + r] / TOPK) : -1;
  }
  __syncthreads();
  float acc[4][4] = {};
  const int tx = tid & 15, ty = tid >> 4;
  for (int k0 = 0; k0 < HID_D; k0 += 16) {
    {
      const int r = tid >> 2, c = (tid & 3) << 2;
      const int tok = toks[r];
      float4 a = make_float4(0.f, 0.f, 0.f, 0.f);
      if (tok >= 0) a = *(const float4*)(x + (size_t)tok * HID_D + (k0 + c));
      As[c + 0][r] = a.x; As[c + 1][r] = a.y; As[c + 2][r] = a.z; As[c + 3][r] = a.w;
      const int rb = tid >> 4, cb = (tid & 15) << 2;
      *(float4*)(&Bs[rb][cb]) = *(const float4*)(B + (size_t)(k0 + rb) * MH_D + (bn + cb));
    }
    __syncthreads();
    #pragma unroll
    for (int kk = 0; kk < 16; ++kk) {
      const float4 a4 = *(const float4*)(&As[kk][ty << 2]);
      const float4 b4 = *(const float4*)(&Bs[kk][tx << 2]);
      const float av[4] = {a4.x, a4.y, a4.z, a4.w};
      const float bv[4] = {b4.x, b4.y, b4.z, b4.w};
      #pragma unroll
      for (int i = 0; i < 4; ++i)
        #pragma unroll
        for (int j = 0; j < 4; ++j)
          acc[i][j] = fmaf(av[i], bv[j], acc[i][j]);
    }
    __syncthreads();
  }
  #pragma unroll
  for (int i = 0; i < 4; ++i) {
    const int r = r0 + (ty << 2) + i;
    if (r < cnt) {
      #pragma unroll
      for (int j = 0; j < 4; ++j) {
        const int col = bn + (tx << 2) + j;
        const float v = fmaxf(acc[i][j] + eb1[e * MH_D + col], 0.f);
        hbuf[(size_t)(base + r) * MH_D + col] = v;
      }
    }
  }
}

// ------------- expert layer 2 + weighted scatter-add into moe_out ----------------------
__global__ __launch_bounds__(256)
void expert_l2(const float* __restrict__ hbuf, const float* __restrict__ ew2,
               const float* __restrict__ eb2, const int* __restrict__ perm,
               const int* __restrict__ offsets, const int* __restrict__ counts,
               const float* __restrict__ topw, float* __restrict__ moe_out) {
  const int e = blockIdx.z;
  const int cnt = counts[e];
  const int r0 = blockIdx.y * 64;
  if (r0 >= cnt) return;
  const int bn = blockIdx.x * 64;
  const float* B = ew2 + (size_t)e * MH_D * HID_D;
  const int base = offsets[e];
  __shared__ float As[16][64];
  __shared__ float Bs[16][64];
  __shared__ int slots[64];
  const int tid = threadIdx.x;
  if (tid < 64) {
    const int r = r0 + tid;
    slots[tid] = (r < cnt) ? perm[base + r] : -1;
  }
  __syncthreads();
  float acc[4][4] = {};
  const int tx = tid & 15, ty = tid >> 4;
  for (int k0 = 0; k0 < MH_D; k0 += 16) {
    {
      const int r = tid >> 2, c = (tid & 3) << 2;
      float4 a = make_float4(0.f, 0.f, 0.f, 0.f);
      if (r0 + r < cnt) a = *(const float4*)(hbuf + (size_t)(base + r0 + r) * MH_D + (k0 + c));
      As[c + 0][r] = a.x; As[c + 1][r] = a.y; As[c + 2][r] = a.z; As[c + 3][r] = a.w;
      const int rb = tid >> 4, cb = (tid & 15) << 2;
      *(float4*)(&Bs[rb][cb]) = *(const float4*)(B + (size_t)(k0 + rb) * HID_D + (bn + cb));
    }
    __syncthreads();
    #pragma unroll
    for (int kk = 0; kk < 16; ++kk) {
      const float4 a4 = *(const float4*)(&As[kk][ty << 2]);
      const float4 b4 = *(const float4*)(&Bs[kk][tx << 2]);
      const float av[4] = {a4.x, a4.y, a4.z, a4.w};
      const float bv[4] = {b4.x, b4.y, b4.z, b4.w};
      #pragma unroll
      for (int i = 0; i < 4; ++i)
        #pragma unroll
        for (int j = 0; j < 4; ++j)
          acc[i][j] = fmaf(av[i], bv[j], acc[i][j]);
    }
    __syncthreads();
  }
  #pragma unroll
  for (int i = 0; i < 4; ++i) {
    const int r = r0 + (ty << 2) + i;
    if (r < cnt) {
      const int slot = slots[(ty << 2) + i];
      const int t = slot / TOPK;
      const float w = topw[slot];
      #pragma unroll
      for (int j = 0; j < 4; ++j) {
        const int col = bn + (tx << 2) + j;
        const float v = (acc[i][j] + eb2[e * HID_D + col]) * w;
        atomicAdd(&moe_out[(size_t)t * HID_D + col], v);
      }
    }
  }
}

// ------------- p2 head: mu = tanh(relu(moe) @ p2_w + p2_b); std broadcast --------------
__global__ __launch_bounds__(256)
void p2_head(const float* __restrict__ xin, const float* __restrict__ w,
             const float* __restrict__ b, const float* __restrict__ stdp,
             float* __restrict__ outp) {
  const int wave = (blockIdx.x * 256 + threadIdx.x) >> 6;
  const int lane = threadIdx.x & 63;
  if (wave >= T_DIM) return;
  const float* xr = xin + (size_t)wave * HID_D;
  float a[ACT_D] = {};
  for (int k = lane; k < HID_D; k += 64) {
    const float xv = fmaxf(xr[k], 0.f);
    const float* wr = w + (size_t)k * ACT_D;
    #pragma unroll
    for (int j = 0; j < ACT_D; ++j) a[j] = fmaf(xv, wr[j], a[j]);
  }
  #pragma unroll
  for (int j = 0; j < ACT_D; ++j) {
    float v = a[j];
    #pragma unroll
    for (int d = 32; d >= 1; d >>= 1) v += __shfl_xor(v, d, 64);
    a[j] = v;
  }
  if (lane == 0) {
    const float sv = stdp[0];
    #pragma unroll
    for (int j = 0; j < ACT_D; ++j) {
      outp[(size_t)wave * ACT_D + j] = tanhf(a[j] + b[j]);
      outp[(size_t)T_DIM * ACT_D + (size_t)wave * ACT_D + j] = sv;
    }
  }
}

__global__ void aux_kernel(const float* __restrict__ imp, const int* __restrict__ counts,
                           float* __restrict__ outp) {
  const int e = threadIdx.x;
  float v = 0.f;
  if (e < NE)
    v = (imp[e] / (float)T_DIM) * ((float)counts[e] / (float)(T_DIM * TOPK));
  #pragma unroll
  for (int d = 32; d >= 1; d >>= 1) v += __shfl_xor(v, d, 64);
  if (e == 0) outp[2 * T_DIM * ACT_D] = (float)NE * v;
}

extern "C" void kernel_launch(void* const* d_in, const int* in_sizes, int n_in,
                              void* d_out, int out_size, void* d_ws, size_t ws_size,
                              hipStream_t stream) {
  const float* obs     = (const float*)d_in[0];
  const float* stdp    = (const float*)d_in[1];
  const float* trunk_w = (const float*)d_in[2];
  const float* trunk_b = (const float*)d_in[3];
  const float* ln_g    = (const float*)d_in[4];
  const float* ln_b    = (const float*)d_in[5];
  const float* p1_w    = (const float*)d_in[6];
  const float* p1_b    = (const float*)d_in[7];
  const float* g1_w    = (const float*)d_in[8];
  const float* g1_b    = (const float*)d_in[9];
  const float* g2_w    = (const float*)d_in[10];
  const float* g2_b    = (const float*)d_in[11];
  const float* ew1     = (const float*)d_in[12];
  const float* eb1     = (const float*)d_in[13];
  const float* ew2     = (const float*)d_in[14];
  const float* eb2     = (const float*)d_in[15];
  const float* p2_w    = (const float*)d_in[16];
  const float* p2_b    = (const float*)d_in[17];
  float* out = (float*)d_out;

  char* p = (char*)d_ws;
  float* h_feat  = (float*)p; p += (size_t)T_DIM * FEAT_D * 4;
  float* x       = (float*)p; p += (size_t)T_DIM * HID_D * 4;
  float* hg      = (float*)p; p += (size_t)T_DIM * GATE_D * 4;
  float* h_moe   = (float*)p; p += (size_t)T_DIM * TOPK * MH_D * 4;
  float* moe_out = (float*)p; p += (size_t)T_DIM * HID_D * 4;
  float* topw    = (float*)p; p += (size_t)T_DIM * TOPK * 4;
  float* imp     = (float*)p; p += 128;
  int* topi      = (int*)p;   p += (size_t)T_DIM * TOPK * 4;
  int* perm      = (int*)p;   p += (size_t)T_DIM * TOPK * 4;
  int* counts    = (int*)p;   p += 128;
  int* offsets   = (int*)p;   p += 256;
  int* fill      = (int*)p;   p += 128;

  hipMemsetAsync(imp, 0, 128, stream);
  hipMemsetAsync(counts, 0, 128, stream);
  hipMemsetAsync(fill, 0, 128, stream);
  hipMemsetAsync(moe_out, 0, (size_t)T_DIM * HID_D * 4, stream);

  // trunk GEMM (no act), then LN+tanh in place
  gemm_bias_act<false><<<dim3(FEAT_D / 64, T_DIM / 64), 256, 0, stream>>>(
      obs, trunk_w, trunk_b, h_feat, T_DIM, FEAT_D, REPR_D);
  ln_tanh<<<T_DIM, 256, 0, stream>>>(h_feat, ln_g, ln_b);
  // p1 (relu)
  gemm_bias_act<true><<<dim3(HID_D / 64, T_DIM / 64), 256, 0, stream>>>(
      h_feat, p1_w, p1_b, x, T_DIM, HID_D, FEAT_D);
  // gate layer 1 (relu)
  gemm_bias_act<true><<<dim3(GATE_D / 64, T_DIM / 64), 256, 0, stream>>>(
      x, g1_w, g1_b, hg, T_DIM, GATE_D, HID_D);
  // gate layer 2 + softmax + top-k + aux accumulation
  gate2_topk<<<T_DIM / 8, 256, 0, stream>>>(hg, g2_w, g2_b, imp, counts, topi, topw);
  scan_offsets<<<1, 64, 0, stream>>>(counts, offsets);
  fill_perm<<<(T_DIM * TOPK) / 256, 256, 0, stream>>>(topi, offsets, fill, perm);
  // grouped expert MLP
  expert_l1<<<dim3(MH_D / 64, T_DIM / 64, NE), 256, 0, stream>>>(
      x, ew1, eb1, perm, offsets, counts, h_moe);
  expert_l2<<<dim3(HID_D / 64, T_DIM / 64, NE), 256, 0, stream>>>(
      h_moe, ew2, eb2, perm, offsets, counts, topw, moe_out);
  // policy head + std broadcast
  p2_head<<<T_DIM / 4, 256, 0, stream>>>(moe_out, p2_w, p2_b, stdp, out);
  aux_kernel<<<1, 64, 0, stream>>>(imp, counts, out);
}

// Round 3
// 647.191 us; speedup vs baseline: 1.6521x; 1.6521x over previous
//
#include <hip/hip_runtime.h>
#include <math.h>

#define T_DIM  4096
#define REPR_D 2048
#define FEAT_D 1024
#define HID_D  1024
#define GATE_D 256
#define MH_D   256
#define NE     32
#define TOPK   4
#define ACT_D  12
#define LN_EPS 1e-5f

typedef unsigned short u16;
typedef __attribute__((ext_vector_type(8))) short short8;
typedef __attribute__((ext_vector_type(4))) float f32x4;
typedef __attribute__((ext_vector_type(4))) unsigned short u16x4;

__device__ __forceinline__ u16 f2bf(float f) {
  unsigned int u = __float_as_uint(f);
  u += 0x7fff + ((u >> 16) & 1);     // round-to-nearest-even
  return (u16)(u >> 16);
}
__device__ __forceinline__ float bf2f(u16 v) {
  return __uint_as_float(((unsigned int)v) << 16);
}

__device__ __forceinline__ void gload16(const u16* g, u16* l) {
  __builtin_amdgcn_global_load_lds(
      (const __attribute__((address_space(1))) unsigned int*)g,
      (__attribute__((address_space(3))) unsigned int*)l, 16, 0, 0);
}

// ============ bf16x3 f32-emulated MFMA GEMM: C = act(A @ Bt^T + bias) ==================
// A: 3 bf16 planes [M][K] (plane stride M*K), Bt: 3 planes [N][K] (stride N*K).
// Includes all split products with i+j<=2 (error ~ f32 GEMM). 128x128 tile, BK=32.
template<bool RELU, bool SPLIT3>
__global__ __launch_bounds__(256)
void gemm_bf16x3(const u16* __restrict__ A, const u16* __restrict__ Bt,
                 const float* __restrict__ bias, float* __restrict__ Cf,
                 u16* __restrict__ Cs, int M, int N, int K) {
  __shared__ u16 lA[3][128 * 32];
  __shared__ u16 lB[3][128 * 32];
  const int tid = threadIdx.x;
  const int bm = blockIdx.y * 128, bn = blockIdx.x * 128;
  const int lane = tid & 63, wid = tid >> 6;
  const int wm = (wid >> 1) * 64, wn = (wid & 1) * 64;
  const size_t sA = (size_t)M * K, sB = (size_t)N * K;
  const u16* pa = A + (size_t)(bm + (tid >> 2)) * K + (tid & 3) * 8;
  const u16* pb = Bt + (size_t)(bn + (tid >> 2)) * K + (tid & 3) * 8;
  u16* la = &lA[0][0] + tid * 8;
  u16* lb = &lB[0][0] + tid * 8;
  f32x4 acc[4][4] = {};
  for (int k0 = 0; k0 < K; k0 += 32) {
    #pragma unroll
    for (int p = 0; p < 3; ++p) {
      gload16(pa + p * sA + k0, la + p * 4096);
      gload16(pa + p * sA + (size_t)64 * K + k0, la + p * 4096 + 2048);
      gload16(pb + p * sB + k0, lb + p * 4096);
      gload16(pb + p * sB + (size_t)64 * K + k0, lb + p * 4096 + 2048);
    }
    __syncthreads();
    short8 af[3][4];
    #pragma unroll
    for (int i = 0; i < 3; ++i)
      #pragma unroll
      for (int m = 0; m < 4; ++m)
        af[i][m] = *(const short8*)&lA[i][(wm + m * 16 + (lane & 15)) * 32 + (lane >> 4) * 8];
    #pragma unroll
    for (int j = 0; j < 3; ++j) {
      short8 bf[4];
      #pragma unroll
      for (int n = 0; n < 4; ++n)
        bf[n] = *(const short8*)&lB[j][(wn + n * 16 + (lane & 15)) * 32 + (lane >> 4) * 8];
      #pragma unroll
      for (int i = 0; i < 3 - j; ++i)
        #pragma unroll
        for (int m = 0; m < 4; ++m)
          #pragma unroll
          for (int n = 0; n < 4; ++n)
            acc[m][n] = __builtin_amdgcn_mfma_f32_16x16x32_bf16(af[i][m], bf[n], acc[m][n], 0, 0, 0);
    }
    __syncthreads();
  }
  const size_t MN = (size_t)M * N;
  #pragma unroll
  for (int n = 0; n < 4; ++n) {
    const int col = bn + wn + n * 16 + (lane & 15);
    const float bz = bias[col];
    #pragma unroll
    for (int m = 0; m < 4; ++m) {
      #pragma unroll
      for (int r = 0; r < 4; ++r) {
        const int row = bm + wm + m * 16 + (lane >> 4) * 4 + r;
        float v = acc[m][n][r] + bz;
        if (RELU) v = fmaxf(v, 0.f);
        const size_t idx = (size_t)row * N + col;
        if (!SPLIT3) {
          Cf[idx] = v;
        } else {
          const u16 v0 = f2bf(v);  const float r1 = v - bf2f(v0);
          const u16 v1 = f2bf(r1); const float r2 = r1 - bf2f(v1);
          Cs[idx] = v0; Cs[idx + MN] = v1; Cs[idx + 2 * MN] = f2bf(r2);
        }
      }
    }
  }
}

// ============ single-plane bf16 MFMA GEMM pieces for the expert (value) path ============
__global__ __launch_bounds__(256)
void expert_l1(const u16* __restrict__ x, const u16* __restrict__ ew1T,
               const float* __restrict__ eb1, const int* __restrict__ perm,
               const int* __restrict__ offsets, const int* __restrict__ counts,
               u16* __restrict__ hbuf) {
  const int e = blockIdx.z;
  const int cnt = counts[e];
  const int r0 = blockIdx.y * 128;
  if (r0 >= cnt) return;
  const int base = offsets[e];
  const int bn = blockIdx.x * 128;
  __shared__ u16 lA[128 * 32];
  __shared__ u16 lB[128 * 32];
  __shared__ int toksm[128];
  const int tid = threadIdx.x;
  if (tid < 128) toksm[tid] = (r0 + tid < cnt) ? (perm[base + r0 + tid] >> 2) : 0;
  __syncthreads();
  const int lane = tid & 63, wid = tid >> 6;
  const int wm = (wid >> 1) * 64, wn = (wid & 1) * 64;
  const u16* pa0 = x + (size_t)toksm[tid >> 2] * HID_D + (tid & 3) * 8;
  const u16* pa1 = x + (size_t)toksm[64 + (tid >> 2)] * HID_D + (tid & 3) * 8;
  const u16* pb0 = ew1T + (size_t)e * MH_D * HID_D + (size_t)(bn + (tid >> 2)) * HID_D + (tid & 3) * 8;
  const u16* pb1 = pb0 + (size_t)64 * HID_D;
  u16* la = lA + tid * 8;
  u16* lb = lB + tid * 8;
  f32x4 acc[4][4] = {};
  for (int k0 = 0; k0 < HID_D; k0 += 32) {
    gload16(pa0 + k0, la);
    gload16(pa1 + k0, la + 2048);
    gload16(pb0 + k0, lb);
    gload16(pb1 + k0, lb + 2048);
    __syncthreads();
    short8 af[4], bf[4];
    #pragma unroll
    for (int m = 0; m < 4; ++m)
      af[m] = *(const short8*)&lA[(wm + m * 16 + (lane & 15)) * 32 + (lane >> 4) * 8];
    #pragma unroll
    for (int n = 0; n < 4; ++n)
      bf[n] = *(const short8*)&lB[(wn + n * 16 + (lane & 15)) * 32 + (lane >> 4) * 8];
    #pragma unroll
    for (int m = 0; m < 4; ++m)
      #pragma unroll
      for (int n = 0; n < 4; ++n)
        acc[m][n] = __builtin_amdgcn_mfma_f32_16x16x32_bf16(af[m], bf[n], acc[m][n], 0, 0, 0);
    __syncthreads();
  }
  #pragma unroll
  for (int n = 0; n < 4; ++n) {
    const int col = bn + wn + n * 16 + (lane & 15);
    const float bz = eb1[e * MH_D + col];
    #pragma unroll
    for (int m = 0; m < 4; ++m) {
      #pragma unroll
      for (int r = 0; r < 4; ++r) {
        const int rl = wm + m * 16 + (lane >> 4) * 4 + r;
        if (r0 + rl < cnt) {
          const float v = fmaxf(acc[m][n][r] + bz, 0.f);
          hbuf[(size_t)(base + r0 + rl) * MH_D + col] = f2bf(v);
        }
      }
    }
  }
}

__global__ __launch_bounds__(256)
void expert_l2(const u16* __restrict__ hbuf, const u16* __restrict__ ew2T,
               const float* __restrict__ eb2, const int* __restrict__ perm,
               const int* __restrict__ offsets, const int* __restrict__ counts,
               const float* __restrict__ topw, float* __restrict__ moe_out) {
  const int e = blockIdx.z;
  const int cnt = counts[e];
  const int r0 = blockIdx.y * 128;
  if (r0 >= cnt) return;
  const int base = offsets[e];
  const int bn = blockIdx.x * 128;
  __shared__ u16 lA[128 * 32];
  __shared__ u16 lB[128 * 32];
  __shared__ int slotm[128];
  const int tid = threadIdx.x;
  if (tid < 128) slotm[tid] = (r0 + tid < cnt) ? perm[base + r0 + tid] : 0;
  __syncthreads();
  const int lane = tid & 63, wid = tid >> 6;
  const int wm = (wid >> 1) * 64, wn = (wid & 1) * 64;
  const int ra = (r0 + (tid >> 2) < cnt) ? r0 + (tid >> 2) : cnt - 1;
  const int rb = (r0 + 64 + (tid >> 2) < cnt) ? r0 + 64 + (tid >> 2) : cnt - 1;
  const u16* pa0 = hbuf + (size_t)(base + ra) * MH_D + (tid & 3) * 8;
  const u16* pa1 = hbuf + (size_t)(base + rb) * MH_D + (tid & 3) * 8;
  const u16* pb0 = ew2T + (size_t)e * HID_D * MH_D + (size_t)(bn + (tid >> 2)) * MH_D + (tid & 3) * 8;
  const u16* pb1 = pb0 + (size_t)64 * MH_D;
  u16* la = lA + tid * 8;
  u16* lb = lB + tid * 8;
  f32x4 acc[4][4] = {};
  for (int k0 = 0; k0 < MH_D; k0 += 32) {
    gload16(pa0 + k0, la);
    gload16(pa1 + k0, la + 2048);
    gload16(pb0 + k0, lb);
    gload16(pb1 + k0, lb + 2048);
    __syncthreads();
    short8 af[4], bf[4];
    #pragma unroll
    for (int m = 0; m < 4; ++m)
      af[m] = *(const short8*)&lA[(wm + m * 16 + (lane & 15)) * 32 + (lane >> 4) * 8];
    #pragma unroll
    for (int n = 0; n < 4; ++n)
      bf[n] = *(const short8*)&lB[(wn + n * 16 + (lane & 15)) * 32 + (lane >> 4) * 8];
    #pragma unroll
    for (int m = 0; m < 4; ++m)
      #pragma unroll
      for (int n = 0; n < 4; ++n)
        acc[m][n] = __builtin_amdgcn_mfma_f32_16x16x32_bf16(af[m], bf[n], acc[m][n], 0, 0, 0);
    __syncthreads();
  }
  #pragma unroll
  for (int n = 0; n < 4; ++n) {
    const int col = bn + wn + n * 16 + (lane & 15);
    const float bz = eb2[e * HID_D + col];
    #pragma unroll
    for (int m = 0; m < 4; ++m) {
      #pragma unroll
      for (int r = 0; r < 4; ++r) {
        const int rl = wm + m * 16 + (lane >> 4) * 4 + r;
        if (r0 + rl < cnt) {
          const int slot = slotm[rl];
          const float w = topw[slot];
          atomicAdd(&moe_out[(size_t)(slot >> 2) * HID_D + col], (acc[m][n][r] + bz) * w);
        }
      }
    }
  }
}

// ============ cast / transpose / split helpers ==========================================
__global__ __launch_bounds__(256)
void cast3_k(const float* __restrict__ in, u16* __restrict__ out, size_t total) {
  const size_t i = ((size_t)blockIdx.x * 256 + threadIdx.x) * 4;
  const float4 v = *(const float4*)(in + i);
  const float vv[4] = {v.x, v.y, v.z, v.w};
  u16x4 o0, o1, o2;
  #pragma unroll
  for (int j = 0; j < 4; ++j) {
    const u16 a0 = f2bf(vv[j]); const float r1 = vv[j] - bf2f(a0);
    const u16 a1 = f2bf(r1);    const float r2 = r1 - bf2f(a1);
    o0[j] = a0; o1[j] = a1; o2[j] = f2bf(r2);
  }
  *(u16x4*)(out + i) = o0;
  *(u16x4*)(out + total + i) = o1;
  *(u16x4*)(out + 2 * total + i) = o2;
}

// in: f32 [K][N], out: 3 bf16 planes [N][K]
__global__ __launch_bounds__(256)
void transpose_cast3(const float* __restrict__ in, u16* __restrict__ out, int K, int N) {
  __shared__ float t[32][33];
  const int bn = blockIdx.x * 32, bk = blockIdx.y * 32;
  const int tx = threadIdx.x & 31, ty = threadIdx.x >> 5;
  const size_t NK = (size_t)N * K;
  #pragma unroll
  for (int i = 0; i < 32; i += 8) t[ty + i][tx] = in[(size_t)(bk + ty + i) * N + bn + tx];
  __syncthreads();
  #pragma unroll
  for (int i = 0; i < 32; i += 8) {
    const float v = t[tx][ty + i];
    const size_t idx = (size_t)(bn + ty + i) * K + bk + tx;
    const u16 v0 = f2bf(v);  const float r1 = v - bf2f(v0);
    const u16 v1 = f2bf(r1); const float r2 = r1 - bf2f(v1);
    out[idx] = v0; out[idx + NK] = v1; out[idx + 2 * NK] = f2bf(r2);
  }
}

// single-plane transpose-cast (expert weights, value path)
__global__ __launch_bounds__(256)
void transpose_cast(const float* __restrict__ in, u16* __restrict__ out, int K, int N) {
  const size_t off = (size_t)blockIdx.z * K * N;
  in += off; out += off;
  __shared__ float t[32][33];
  const int bn = blockIdx.x * 32, bk = blockIdx.y * 32;
  const int tx = threadIdx.x & 31, ty = threadIdx.x >> 5;
  #pragma unroll
  for (int i = 0; i < 32; i += 8) t[ty + i][tx] = in[(size_t)(bk + ty + i) * N + bn + tx];
  __syncthreads();
  #pragma unroll
  for (int i = 0; i < 32; i += 8) out[(size_t)(bn + ty + i) * K + bk + tx] = f2bf(t[tx][ty + i]);
}

// ============ LayerNorm + tanh: f32 in -> 3 bf16 planes out =============================
__global__ __launch_bounds__(256)
void ln_tanh3(const float* __restrict__ in, u16* __restrict__ outp,
              const float* __restrict__ g, const float* __restrict__ b) {
  const int row = blockIdx.x, tid = threadIdx.x;
  const float4 v = ((const float4*)(in + (size_t)row * FEAT_D))[tid];
  float s = v.x + v.y + v.z + v.w;
  float ss = v.x * v.x + v.y * v.y + v.z * v.z + v.w * v.w;
  #pragma unroll
  for (int d = 32; d >= 1; d >>= 1) { s += __shfl_xor(s, d, 64); ss += __shfl_xor(ss, d, 64); }
  __shared__ float red[2][4];
  const int w = tid >> 6;
  if ((tid & 63) == 0) { red[0][w] = s; red[1][w] = ss; }
  __syncthreads();
  s  = red[0][0] + red[0][1] + red[0][2] + red[0][3];
  ss = red[1][0] + red[1][1] + red[1][2] + red[1][3];
  const float m = s * (1.f / FEAT_D);
  const float inv = rsqrtf(ss * (1.f / FEAT_D) - m * m + LN_EPS);
  const float4 gg = ((const float4*)g)[tid];
  const float4 bb = ((const float4*)b)[tid];
  const float tv[4] = {tanhf((v.x - m) * inv * gg.x + bb.x),
                       tanhf((v.y - m) * inv * gg.y + bb.y),
                       tanhf((v.z - m) * inv * gg.z + bb.z),
                       tanhf((v.w - m) * inv * gg.w + bb.w)};
  const size_t PS = (size_t)T_DIM * FEAT_D;
  u16x4 o0, o1, o2;
  #pragma unroll
  for (int j = 0; j < 4; ++j) {
    const u16 a0 = f2bf(tv[j]); const float r1 = tv[j] - bf2f(a0);
    const u16 a1 = f2bf(r1);    const float r2 = r1 - bf2f(a1);
    o0[j] = a0; o1[j] = a1; o2[j] = f2bf(r2);
  }
  ((u16x4*)(outp + (size_t)row * FEAT_D))[tid] = o0;
  ((u16x4*)(outp + PS + (size_t)row * FEAT_D))[tid] = o1;
  ((u16x4*)(outp + 2 * PS + (size_t)row * FEAT_D))[tid] = o2;
}

// ============ gate layer 2 + softmax + top-4 + renorm + aux (f32, as R1) ================
__global__ __launch_bounds__(256)
void gate2_topk(const float* __restrict__ hg, const float* __restrict__ g2w,
                const float* __restrict__ g2b, float* __restrict__ imp,
                int* __restrict__ counts, int* __restrict__ topi, float* __restrict__ topw) {
  __shared__ float wsm[GATE_D][NE];
  __shared__ float rows[8][GATE_D];
  __shared__ float pacc[8][NE];
  const int tid = threadIdx.x;
  const int t0 = blockIdx.x * 8;
  for (int i = tid; i < GATE_D * NE; i += 256) wsm[i / NE][i % NE] = g2w[i];
  for (int i = tid; i < 8 * GATE_D; i += 256)
    rows[i / GATE_D][i % GATE_D] = hg[(size_t)(t0 + i / GATE_D) * GATE_D + (i % GATE_D)];
  __syncthreads();
  const int tl = tid >> 5;
  const int e  = tid & 31;
  const int t  = t0 + tl;
  float logit = g2b[e];
  for (int k = 0; k < GATE_D; ++k) logit = fmaf(rows[tl][k], wsm[k][e], logit);
  float m = logit;
  #pragma unroll
  for (int d = 16; d >= 1; d >>= 1) m = fmaxf(m, __shfl_xor(m, d, 32));
  const float p = expf(logit - m);
  float ssum = p;
  #pragma unroll
  for (int d = 16; d >= 1; d >>= 1) ssum += __shfl_xor(ssum, d, 32);
  const float prob = p / ssum;
  pacc[tl][e] = prob;
  __syncthreads();
  if (tl == 0) {
    float a = 0.f;
    #pragma unroll
    for (int q = 0; q < 8; ++q) a += pacc[q][e];
    atomicAdd(&imp[e], a);
  }
  float cur = prob;
  float wv[TOPK]; int wi[TOPK];
  #pragma unroll
  for (int it = 0; it < TOPK; ++it) {
    float v = cur; int idx = e;
    #pragma unroll
    for (int d = 16; d >= 1; d >>= 1) {
      float v2 = __shfl_xor(v, d, 32);
      int   i2 = __shfl_xor(idx, d, 32);
      if (v2 > v || (v2 == v && i2 < idx)) { v = v2; idx = i2; }
    }
    wv[it] = v; wi[it] = idx;
    if (e == idx) cur = -1e30f;
  }
  if (e == 0) {
    const float s4 = wv[0] + wv[1] + wv[2] + wv[3];
    #pragma unroll
    for (int k2 = 0; k2 < TOPK; ++k2) {
      topi[t * TOPK + k2] = wi[k2];
      topw[t * TOPK + k2] = wv[k2] / s4;
      atomicAdd(&counts[wi[k2]], 1);
    }
  }
}

__global__ void scan_offsets(const int* __restrict__ counts, int* __restrict__ offsets) {
  if (threadIdx.x == 0) {
    int a = 0;
    for (int e = 0; e < NE; ++e) { offsets[e] = a; a += counts[e]; }
    offsets[NE] = a;
  }
}

__global__ __launch_bounds__(256)
void fill_perm(const int* __restrict__ topi, const int* __restrict__ offsets,
               int* __restrict__ fill, int* __restrict__ perm) {
  const int s = blockIdx.x * 256 + threadIdx.x;
  const int e = topi[s];
  const int pos = atomicAdd(&fill[e], 1);
  perm[offsets[e] + pos] = s;
}

// ============ p2 head + std broadcast ===================================================
__global__ __launch_bounds__(256)
void p2_head(const float* __restrict__ xin, const float* __restrict__ w,
             const float* __restrict__ b, const float* __restrict__ stdp,
             float* __restrict__ outp) {
  const int wave = (blockIdx.x * 256 + threadIdx.x) >> 6;
  const int lane = threadIdx.x & 63;
  if (wave >= T_DIM) return;
  const float* xr = xin + (size_t)wave * HID_D;
  float a[ACT_D] = {};
  for (int k = lane; k < HID_D; k += 64) {
    const float xv = fmaxf(xr[k], 0.f);
    const float* wr = w + (size_t)k * ACT_D;
    #pragma unroll
    for (int j = 0; j < ACT_D; ++j) a[j] = fmaf(xv, wr[j], a[j]);
  }
  #pragma unroll
  for (int j = 0; j < ACT_D; ++j) {
    float v = a[j];
    #pragma unroll
    for (int d = 32; d >= 1; d >>= 1) v += __shfl_xor(v, d, 64);
    a[j] = v;
  }
  if (lane == 0) {
    const float sv = stdp[0];
    #pragma unroll
    for (int j = 0; j < ACT_D; ++j) {
      outp[(size_t)wave * ACT_D + j] = tanhf(a[j] + b[j]);
      outp[(size_t)T_DIM * ACT_D + (size_t)wave * ACT_D + j] = sv;
    }
  }
}

__global__ void aux_kernel(const float* __restrict__ imp, const int* __restrict__ counts,
                           float* __restrict__ outp) {
  const int e = threadIdx.x;
  float v = 0.f;
  if (e < NE)
    v = (imp[e] / (float)T_DIM) * ((float)counts[e] / (float)(T_DIM * TOPK));
  #pragma unroll
  for (int d = 32; d >= 1; d >>= 1) v += __shfl_xor(v, d, 64);
  if (e == 0) outp[2 * T_DIM * ACT_D] = (float)NE * v;
}

extern "C" void kernel_launch(void* const* d_in, const int* in_sizes, int n_in,
                              void* d_out, int out_size, void* d_ws, size_t ws_size,
                              hipStream_t stream) {
  const float* obs     = (const float*)d_in[0];
  const float* stdp    = (const float*)d_in[1];
  const float* trunk_w = (const float*)d_in[2];
  const float* trunk_b = (const float*)d_in[3];
  const float* ln_g    = (const float*)d_in[4];
  const float* ln_b    = (const float*)d_in[5];
  const float* p1_w    = (const float*)d_in[6];
  const float* p1_b    = (const float*)d_in[7];
  const float* g1_w    = (const float*)d_in[8];
  const float* g1_b    = (const float*)d_in[9];
  const float* g2_w    = (const float*)d_in[10];
  const float* g2_b    = (const float*)d_in[11];
  const float* ew1     = (const float*)d_in[12];
  const float* eb1     = (const float*)d_in[13];
  const float* ew2     = (const float*)d_in[14];
  const float* eb2     = (const float*)d_in[15];
  const float* p2_w    = (const float*)d_in[16];
  const float* p2_b    = (const float*)d_in[17];
  float* out = (float*)d_out;

  // ---- workspace layout with lifetime overlays ----
  char* p = (char*)d_ws;
  // [A] 50.4 MB: obs3 (3 planes T x REPR) -> then h3 (3 x T x FEAT) + x3 (3 x T x HID)
  u16* obs3 = (u16*)p;
  u16* h3   = (u16*)p;
  u16* x3   = (u16*)(p + 3 * (size_t)T_DIM * FEAT_D * 2);
  p += 3 * (size_t)T_DIM * REPR_D * 2;
  // [B] 12.6 MB: trunk_wT3 -> then p1_wT3 (6.3) + g1_wT3 (1.6)
  u16* trunk_wT3 = (u16*)p;
  u16* p1_wT3    = (u16*)p;
  u16* g1_wT3    = (u16*)(p + 3 * (size_t)FEAT_D * HID_D * 2);
  p += 3 * (size_t)FEAT_D * REPR_D * 2;
  // [C] 16.8 MB: h_pre f32 -> then moe_out f32
  float* h_pre   = (float*)p;
  float* moe_out = (float*)p;
  p += (size_t)T_DIM * FEAT_D * 4;
  u16* ew1T = (u16*)p; p += (size_t)NE * HID_D * MH_D * 2;   // 16.8 MB
  u16* ew2T = (u16*)p; p += (size_t)NE * HID_D * MH_D * 2;   // 16.8 MB
  u16* hbuf = (u16*)p; p += (size_t)T_DIM * TOPK * MH_D * 2; // 8.4 MB
  float* hg = (float*)p; p += (size_t)T_DIM * GATE_D * 4;    // 4.2 MB
  float* topw    = (float*)p; p += (size_t)T_DIM * TOPK * 4;
  int*   topi    = (int*)p;   p += (size_t)T_DIM * TOPK * 4;
  int*   perm    = (int*)p;   p += (size_t)T_DIM * TOPK * 4;
  float* imp     = (float*)p; p += 128;
  int*   counts  = (int*)p;   p += 128;
  int*   offsets = (int*)p;   p += 256;
  int*   fill    = (int*)p;   p += 128;

  hipMemsetAsync(imp, 0, 128, stream);
  hipMemsetAsync(counts, 0, 128, stream);
  hipMemsetAsync(fill, 0, 128, stream);

  // obs + trunk_w -> 3-plane splits
  cast3_k<<<(T_DIM * REPR_D) / 1024, 256, 0, stream>>>(obs, obs3, (size_t)T_DIM * REPR_D);
  transpose_cast3<<<dim3(FEAT_D / 32, REPR_D / 32), 256, 0, stream>>>(trunk_w, trunk_wT3, REPR_D, FEAT_D);

  // trunk (f32-grade): h_pre = obs @ trunk_w + b
  gemm_bf16x3<false, false><<<dim3(FEAT_D / 128, T_DIM / 128), 256, 0, stream>>>(
      obs3, trunk_wT3, trunk_b, h_pre, nullptr, T_DIM, FEAT_D, REPR_D);
  // [B] reuse: p1/g1 weight splits (trunk_wT3 dead)
  transpose_cast3<<<dim3(HID_D / 32, FEAT_D / 32), 256, 0, stream>>>(p1_w, p1_wT3, FEAT_D, HID_D);
  transpose_cast3<<<dim3(GATE_D / 32, HID_D / 32), 256, 0, stream>>>(g1_w, g1_wT3, HID_D, GATE_D);

  // LN + tanh -> h3 planes ([A] reuse: obs3 dead)
  ln_tanh3<<<T_DIM, 256, 0, stream>>>(h_pre, h3, ln_g, ln_b);
  // [C] reuse: moe_out (h_pre dead)
  hipMemsetAsync(moe_out, 0, (size_t)T_DIM * HID_D * 4, stream);

  // p1 (f32-grade): x3 = split3(relu(h @ p1_w + b))
  gemm_bf16x3<true, true><<<dim3(HID_D / 128, T_DIM / 128), 256, 0, stream>>>(
      h3, p1_wT3, p1_b, nullptr, x3, T_DIM, HID_D, FEAT_D);
  // gate1 (f32-grade): hg = relu(x @ g1_w + b)
  gemm_bf16x3<true, false><<<dim3(GATE_D / 128, T_DIM / 128), 256, 0, stream>>>(
      x3, g1_wT3, g1_b, hg, nullptr, T_DIM, GATE_D, HID_D);

  gate2_topk<<<T_DIM / 8, 256, 0, stream>>>(hg, g2_w, g2_b, imp, counts, topi, topw);
  scan_offsets<<<1, 64, 0, stream>>>(counts, offsets);
  fill_perm<<<(T_DIM * TOPK) / 256, 256, 0, stream>>>(topi, offsets, fill, perm);

  // expert value path (bf16): x plane0 = bf16(x)
  transpose_cast<<<dim3(MH_D / 32, HID_D / 32, NE), 256, 0, stream>>>(ew1, ew1T, HID_D, MH_D);
  transpose_cast<<<dim3(HID_D / 32, MH_D / 32, NE), 256, 0, stream>>>(ew2, ew2T, MH_D, HID_D);
  expert_l1<<<dim3(MH_D / 128, 32, NE), 256, 0, stream>>>(
      x3, ew1T, eb1, perm, offsets, counts, hbuf);
  expert_l2<<<dim3(HID_D / 128, 32, NE), 256, 0, stream>>>(
      hbuf, ew2T, eb2, perm, offsets, counts, topw, moe_out);

  p2_head<<<T_DIM / 4, 256, 0, stream>>>(moe_out, p2_w, p2_b, stdp, out);
  aux_kernel<<<1, 64, 0, stream>>>(imp, counts, out);
}

// Round 4
// 510.876 us; speedup vs baseline: 2.0929x; 1.2668x over previous
//
#include <hip/hip_runtime.h>
#include <math.h>

#define T_DIM  4096
#define REPR_D 2048
#define FEAT_D 1024
#define HID_D  1024
#define GATE_D 256
#define MH_D   256
#define NE     32
#define TOPK   4
#define ACT_D  12
#define LN_EPS 1e-5f

typedef unsigned short u16;
typedef __attribute__((ext_vector_type(8))) short short8;
typedef __attribute__((ext_vector_type(4))) float f32x4;
typedef __attribute__((ext_vector_type(4))) unsigned short u16x4;

__device__ __forceinline__ u16 f2bf(float f) {
  unsigned int u = __float_as_uint(f);
  u += 0x7fff + ((u >> 16) & 1);     // round-to-nearest-even
  return (u16)(u >> 16);
}
__device__ __forceinline__ float bf2f(u16 v) {
  return __uint_as_float(((unsigned int)v) << 16);
}

__device__ __forceinline__ void gload16(const u16* g, u16* l) {
  __builtin_amdgcn_global_load_lds(
      (const __attribute__((address_space(1))) unsigned int*)g,
      (__attribute__((address_space(3))) unsigned int*)l, 16, 0, 0);
}

// ============ bf16x3 f32-emulated MFMA GEMM, split-K partials ===========================
// A: 3 planes [M][K], Bt: 3 planes [N][K]. gridDim.z = K-slices; slice z accumulates
// K-range [z*K/nz, (z+1)*K/nz) in f32 and writes raw partial to Cp + z*M*N.
// No bias / act here (folded into consumers). 128x128 tile, BK=32, 4 waves.
__global__ __launch_bounds__(256)
void gemm_bf16x3_sk(const u16* __restrict__ A, const u16* __restrict__ Bt,
                    float* __restrict__ Cp, int M, int N, int K) {
  __shared__ u16 lA[3][128 * 32];
  __shared__ u16 lB[3][128 * 32];
  const int tid = threadIdx.x;
  const int bm = blockIdx.y * 128, bn = blockIdx.x * 128;
  const int ksl = K / gridDim.z;
  const int kbeg = blockIdx.z * ksl, kend = kbeg + ksl;
  const int lane = tid & 63, wid = tid >> 6;
  const int wm = (wid >> 1) * 64, wn = (wid & 1) * 64;
  const size_t sA = (size_t)M * K, sB = (size_t)N * K;
  const u16* pa = A + (size_t)(bm + (tid >> 2)) * K + (tid & 3) * 8;
  const u16* pb = Bt + (size_t)(bn + (tid >> 2)) * K + (tid & 3) * 8;
  u16* la = &lA[0][0] + tid * 8;
  u16* lb = &lB[0][0] + tid * 8;
  f32x4 acc[4][4] = {};
  for (int k0 = kbeg; k0 < kend; k0 += 32) {
    #pragma unroll
    for (int p = 0; p < 3; ++p) {
      gload16(pa + p * sA + k0, la + p * 4096);
      gload16(pa + p * sA + (size_t)64 * K + k0, la + p * 4096 + 2048);
      gload16(pb + p * sB + k0, lb + p * 4096);
      gload16(pb + p * sB + (size_t)64 * K + k0, lb + p * 4096 + 2048);
    }
    __syncthreads();
    short8 af[3][4];
    #pragma unroll
    for (int i = 0; i < 3; ++i)
      #pragma unroll
      for (int m = 0; m < 4; ++m)
        af[i][m] = *(const short8*)&lA[i][(wm + m * 16 + (lane & 15)) * 32 + (lane >> 4) * 8];
    #pragma unroll
    for (int j = 0; j < 3; ++j) {
      short8 bfr[4];
      #pragma unroll
      for (int n = 0; n < 4; ++n)
        bfr[n] = *(const short8*)&lB[j][(wn + n * 16 + (lane & 15)) * 32 + (lane >> 4) * 8];
      #pragma unroll
      for (int i = 0; i < 3 - j; ++i)
        #pragma unroll
        for (int m = 0; m < 4; ++m)
          #pragma unroll
          for (int n = 0; n < 4; ++n)
            acc[m][n] = __builtin_amdgcn_mfma_f32_16x16x32_bf16(af[i][m], bfr[n], acc[m][n], 0, 0, 0);
    }
    __syncthreads();
  }
  float* Co = Cp + (size_t)blockIdx.z * M * N;
  #pragma unroll
  for (int n = 0; n < 4; ++n) {
    const int col = bn + wn + n * 16 + (lane & 15);
    #pragma unroll
    for (int m = 0; m < 4; ++m) {
      #pragma unroll
      for (int r = 0; r < 4; ++r) {
        const int row = bm + wm + m * 16 + (lane >> 4) * 4 + r;
        Co[(size_t)row * N + col] = acc[m][n][r];
      }
    }
  }
}

// ============ single-plane bf16 MFMA expert GEMMs ======================================
__global__ __launch_bounds__(256)
void expert_l1(const u16* __restrict__ x, const u16* __restrict__ ew1T,
               const float* __restrict__ eb1, const int* __restrict__ perm,
               const int* __restrict__ offsets, const int* __restrict__ counts,
               u16* __restrict__ hbuf) {
  const int e = blockIdx.z;
  const int cnt = counts[e];
  const int r0 = blockIdx.y * 128;
  if (r0 >= cnt) return;
  const int base = offsets[e];
  const int bn = blockIdx.x * 128;
  __shared__ u16 lA[128 * 32];
  __shared__ u16 lB[128 * 32];
  __shared__ int toksm[128];
  const int tid = threadIdx.x;
  if (tid < 128) toksm[tid] = (r0 + tid < cnt) ? (perm[base + r0 + tid] >> 2) : 0;
  __syncthreads();
  const int lane = tid & 63, wid = tid >> 6;
  const int wm = (wid >> 1) * 64, wn = (wid & 1) * 64;
  const u16* pa0 = x + (size_t)toksm[tid >> 2] * HID_D + (tid & 3) * 8;
  const u16* pa1 = x + (size_t)toksm[64 + (tid >> 2)] * HID_D + (tid & 3) * 8;
  const u16* pb0 = ew1T + (size_t)e * MH_D * HID_D + (size_t)(bn + (tid >> 2)) * HID_D + (tid & 3) * 8;
  const u16* pb1 = pb0 + (size_t)64 * HID_D;
  u16* la = lA + tid * 8;
  u16* lb = lB + tid * 8;
  f32x4 acc[4][4] = {};
  for (int k0 = 0; k0 < HID_D; k0 += 32) {
    gload16(pa0 + k0, la);
    gload16(pa1 + k0, la + 2048);
    gload16(pb0 + k0, lb);
    gload16(pb1 + k0, lb + 2048);
    __syncthreads();
    short8 af[4], bfr[4];
    #pragma unroll
    for (int m = 0; m < 4; ++m)
      af[m] = *(const short8*)&lA[(wm + m * 16 + (lane & 15)) * 32 + (lane >> 4) * 8];
    #pragma unroll
    for (int n = 0; n < 4; ++n)
      bfr[n] = *(const short8*)&lB[(wn + n * 16 + (lane & 15)) * 32 + (lane >> 4) * 8];
    #pragma unroll
    for (int m = 0; m < 4; ++m)
      #pragma unroll
      for (int n = 0; n < 4; ++n)
        acc[m][n] = __builtin_amdgcn_mfma_f32_16x16x32_bf16(af[m], bfr[n], acc[m][n], 0, 0, 0);
    __syncthreads();
  }
  #pragma unroll
  for (int n = 0; n < 4; ++n) {
    const int col = bn + wn + n * 16 + (lane & 15);
    const float bz = eb1[e * MH_D + col];
    #pragma unroll
    for (int m = 0; m < 4; ++m) {
      #pragma unroll
      for (int r = 0; r < 4; ++r) {
        const int rl = wm + m * 16 + (lane >> 4) * 4 + r;
        if (r0 + rl < cnt) {
          const float v = fmaxf(acc[m][n][r] + bz, 0.f);
          hbuf[(size_t)(base + r0 + rl) * MH_D + col] = f2bf(v);
        }
      }
    }
  }
}

// expert layer 2: writes per-slot rows (bias included, NO combine weight, NO relu)
__global__ __launch_bounds__(256)
void expert_l2(const u16* __restrict__ hbuf, const u16* __restrict__ ew2T,
               const float* __restrict__ eb2, const int* __restrict__ offsets,
               const int* __restrict__ counts, u16* __restrict__ ybuf) {
  const int e = blockIdx.z;
  const int cnt = counts[e];
  const int r0 = blockIdx.y * 128;
  if (r0 >= cnt) return;
  const int base = offsets[e];
  const int bn = blockIdx.x * 128;
  __shared__ u16 lA[128 * 32];
  __shared__ u16 lB[128 * 32];
  const int tid = threadIdx.x;
  const int lane = tid & 63, wid = tid >> 6;
  const int wm = (wid >> 1) * 64, wn = (wid & 1) * 64;
  const int ra = (r0 + (tid >> 2) < cnt) ? r0 + (tid >> 2) : cnt - 1;
  const int rb = (r0 + 64 + (tid >> 2) < cnt) ? r0 + 64 + (tid >> 2) : cnt - 1;
  const u16* pa0 = hbuf + (size_t)(base + ra) * MH_D + (tid & 3) * 8;
  const u16* pa1 = hbuf + (size_t)(base + rb) * MH_D + (tid & 3) * 8;
  const u16* pb0 = ew2T + (size_t)e * HID_D * MH_D + (size_t)(bn + (tid >> 2)) * MH_D + (tid & 3) * 8;
  const u16* pb1 = pb0 + (size_t)64 * MH_D;
  u16* la = lA + tid * 8;
  u16* lb = lB + tid * 8;
  f32x4 acc[4][4] = {};
  for (int k0 = 0; k0 < MH_D; k0 += 32) {
    gload16(pa0 + k0, la);
    gload16(pa1 + k0, la + 2048);
    gload16(pb0 + k0, lb);
    gload16(pb1 + k0, lb + 2048);
    __syncthreads();
    short8 af[4], bfr[4];
    #pragma unroll
    for (int m = 0; m < 4; ++m)
      af[m] = *(const short8*)&lA[(wm + m * 16 + (lane & 15)) * 32 + (lane >> 4) * 8];
    #pragma unroll
    for (int n = 0; n < 4; ++n)
      bfr[n] = *(const short8*)&lB[(wn + n * 16 + (lane & 15)) * 32 + (lane >> 4) * 8];
    #pragma unroll
    for (int m = 0; m < 4; ++m)
      #pragma unroll
      for (int n = 0; n < 4; ++n)
        acc[m][n] = __builtin_amdgcn_mfma_f32_16x16x32_bf16(af[m], bfr[n], acc[m][n], 0, 0, 0);
    __syncthreads();
  }
  #pragma unroll
  for (int n = 0; n < 4; ++n) {
    const int col = bn + wn + n * 16 + (lane & 15);
    const float bz = eb2[e * HID_D + col];
    #pragma unroll
    for (int m = 0; m < 4; ++m) {
      #pragma unroll
      for (int r = 0; r < 4; ++r) {
        const int rl = wm + m * 16 + (lane >> 4) * 4 + r;
        if (r0 + rl < cnt)
          ybuf[(size_t)(base + r0 + rl) * HID_D + col] = f2bf(acc[m][n][r] + bz);
      }
    }
  }
}

// ============ cast / transpose / split helpers ==========================================
__global__ __launch_bounds__(256)
void cast3_k(const float* __restrict__ in, u16* __restrict__ out, size_t total) {
  const size_t i = ((size_t)blockIdx.x * 256 + threadIdx.x) * 4;
  const float4 v = *(const float4*)(in + i);
  const float vv[4] = {v.x, v.y, v.z, v.w};
  u16x4 o0, o1, o2;
  #pragma unroll
  for (int j = 0; j < 4; ++j) {
    const u16 a0 = f2bf(vv[j]); const float r1 = vv[j] - bf2f(a0);
    const u16 a1 = f2bf(r1);    const float r2 = r1 - bf2f(a1);
    o0[j] = a0; o1[j] = a1; o2[j] = f2bf(r2);
  }
  *(u16x4*)(out + i) = o0;
  *(u16x4*)(out + total + i) = o1;
  *(u16x4*)(out + 2 * total + i) = o2;
}

// in: f32 [K][N], out: 3 bf16 planes [N][K]
__global__ __launch_bounds__(256)
void transpose_cast3(const float* __restrict__ in, u16* __restrict__ out, int K, int N) {
  __shared__ float t[32][33];
  const int bn = blockIdx.x * 32, bk = blockIdx.y * 32;
  const int tx = threadIdx.x & 31, ty = threadIdx.x >> 5;
  const size_t NK = (size_t)N * K;
  #pragma unroll
  for (int i = 0; i < 32; i += 8) t[ty + i][tx] = in[(size_t)(bk + ty + i) * N + bn + tx];
  __syncthreads();
  #pragma unroll
  for (int i = 0; i < 32; i += 8) {
    const float v = t[tx][ty + i];
    const size_t idx = (size_t)(bn + ty + i) * K + bk + tx;
    const u16 v0 = f2bf(v);  const float r1 = v - bf2f(v0);
    const u16 v1 = f2bf(r1); const float r2 = r1 - bf2f(v1);
    out[idx] = v0; out[idx + NK] = v1; out[idx + 2 * NK] = f2bf(r2);
  }
}

// single-plane transpose-cast (expert weights)
__global__ __launch_bounds__(256)
void transpose_cast(const float* __restrict__ in, u16* __restrict__ out, int K, int N) {
  const size_t off = (size_t)blockIdx.z * K * N;
  in += off; out += off;
  __shared__ float t[32][33];
  const int bn = blockIdx.x * 32, bk = blockIdx.y * 32;
  const int tx = threadIdx.x & 31, ty = threadIdx.x >> 5;
  #pragma unroll
  for (int i = 0; i < 32; i += 8) t[ty + i][tx] = in[(size_t)(bk + ty + i) * N + bn + tx];
  __syncthreads();
  #pragma unroll
  for (int i = 0; i < 32; i += 8) out[(size_t)(bn + ty + i) * K + bk + tx] = f2bf(t[tx][ty + i]);
}

// ============ LN + tanh: sums 2 trunk partials + bias -> 3 bf16 planes ==================
__global__ __launch_bounds__(256)
void ln_tanh3(const float* __restrict__ hp, const float* __restrict__ tb,
              u16* __restrict__ outp, const float* __restrict__ g,
              const float* __restrict__ b) {
  const int row = blockIdx.x, tid = threadIdx.x;
  const size_t MN = (size_t)T_DIM * FEAT_D;
  const float4 va = ((const float4*)(hp + (size_t)row * FEAT_D))[tid];
  const float4 vb = ((const float4*)(hp + MN + (size_t)row * FEAT_D))[tid];
  const float4 vt = ((const float4*)tb)[tid];
  float4 v;
  v.x = va.x + vb.x + vt.x; v.y = va.y + vb.y + vt.y;
  v.z = va.z + vb.z + vt.z; v.w = va.w + vb.w + vt.w;
  float s = v.x + v.y + v.z + v.w;
  float ss = v.x * v.x + v.y * v.y + v.z * v.z + v.w * v.w;
  #pragma unroll
  for (int d = 32; d >= 1; d >>= 1) { s += __shfl_xor(s, d, 64); ss += __shfl_xor(ss, d, 64); }
  __shared__ float red[2][4];
  const int w = tid >> 6;
  if ((tid & 63) == 0) { red[0][w] = s; red[1][w] = ss; }
  __syncthreads();
  s  = red[0][0] + red[0][1] + red[0][2] + red[0][3];
  ss = red[1][0] + red[1][1] + red[1][2] + red[1][3];
  const float m = s * (1.f / FEAT_D);
  const float inv = rsqrtf(ss * (1.f / FEAT_D) - m * m + LN_EPS);
  const float4 gg = ((const float4*)g)[tid];
  const float4 bb = ((const float4*)b)[tid];
  const float tv[4] = {tanhf((v.x - m) * inv * gg.x + bb.x),
                       tanhf((v.y - m) * inv * gg.y + bb.y),
                       tanhf((v.z - m) * inv * gg.z + bb.z),
                       tanhf((v.w - m) * inv * gg.w + bb.w)};
  u16x4 o0, o1, o2;
  #pragma unroll
  for (int j = 0; j < 4; ++j) {
    const u16 a0 = f2bf(tv[j]); const float r1 = tv[j] - bf2f(a0);
    const u16 a1 = f2bf(r1);    const float r2 = r1 - bf2f(a1);
    o0[j] = a0; o1[j] = a1; o2[j] = f2bf(r2);
  }
  ((u16x4*)(outp + (size_t)row * FEAT_D))[tid] = o0;
  ((u16x4*)(outp + MN + (size_t)row * FEAT_D))[tid] = o1;
  ((u16x4*)(outp + 2 * MN + (size_t)row * FEAT_D))[tid] = o2;
}

// ============ p1 combiner: sum 2 partials + bias, relu, split3 ==========================
__global__ __launch_bounds__(256)
void combine2_relu_split3(const float* __restrict__ P, const float* __restrict__ bias,
                          u16* __restrict__ out3) {
  const size_t MN = (size_t)T_DIM * HID_D;
  const size_t i = ((size_t)blockIdx.x * 256 + threadIdx.x) * 4;
  const float4 a = *(const float4*)(P + i);
  const float4 b = *(const float4*)(P + MN + i);
  const float4 bz = *(const float4*)(bias + (i & (HID_D - 1)));
  const float vv[4] = {fmaxf(a.x + b.x + bz.x, 0.f), fmaxf(a.y + b.y + bz.y, 0.f),
                       fmaxf(a.z + b.z + bz.z, 0.f), fmaxf(a.w + b.w + bz.w, 0.f)};
  u16x4 o0, o1, o2;
  #pragma unroll
  for (int j = 0; j < 4; ++j) {
    const u16 a0 = f2bf(vv[j]); const float r1 = vv[j] - bf2f(a0);
    const u16 a1 = f2bf(r1);    const float r2 = r1 - bf2f(a1);
    o0[j] = a0; o1[j] = a1; o2[j] = f2bf(r2);
  }
  *(u16x4*)(out3 + i) = o0;
  *(u16x4*)(out3 + MN + i) = o1;
  *(u16x4*)(out3 + 2 * MN + i) = o2;
}

// ============ gate2: sums 4 gate1 partials + bias + relu, softmax, top-4, aux ==========
__global__ __launch_bounds__(256)
void gate2_topk(const float* __restrict__ hgP, const float* __restrict__ g1b,
                const float* __restrict__ g2w, const float* __restrict__ g2b,
                float* __restrict__ imp, int* __restrict__ counts,
                int* __restrict__ topi, float* __restrict__ topw) {
  __shared__ float wsm[GATE_D][NE];
  __shared__ float rows[8][GATE_D];
  __shared__ float pacc[8][NE];
  const int tid = threadIdx.x;
  const int t0 = blockIdx.x * 8;
  const size_t TG = (size_t)T_DIM * GATE_D;
  for (int i = tid; i < GATE_D * NE; i += 256) wsm[i / NE][i % NE] = g2w[i];
  for (int i = tid; i < 8 * GATE_D; i += 256) {
    const int r = i / GATE_D, c = i % GATE_D;
    const size_t idx = (size_t)(t0 + r) * GATE_D + c;
    const float v = hgP[idx] + hgP[TG + idx] + hgP[2 * TG + idx] + hgP[3 * TG + idx] + g1b[c];
    rows[r][c] = fmaxf(v, 0.f);
  }
  __syncthreads();
  const int tl = tid >> 5;
  const int e  = tid & 31;
  const int t  = t0 + tl;
  float logit = g2b[e];
  for (int k = 0; k < GATE_D; ++k) logit = fmaf(rows[tl][k], wsm[k][e], logit);
  float m = logit;
  #pragma unroll
  for (int d = 16; d >= 1; d >>= 1) m = fmaxf(m, __shfl_xor(m, d, 32));
  const float p = expf(logit - m);
  float ssum = p;
  #pragma unroll
  for (int d = 16; d >= 1; d >>= 1) ssum += __shfl_xor(ssum, d, 32);
  const float prob = p / ssum;
  pacc[tl][e] = prob;
  __syncthreads();
  if (tl == 0) {
    float a = 0.f;
    #pragma unroll
    for (int q = 0; q < 8; ++q) a += pacc[q][e];
    atomicAdd(&imp[e], a);
  }
  float cur = prob;
  float wv[TOPK]; int wi[TOPK];
  #pragma unroll
  for (int it = 0; it < TOPK; ++it) {
    float v = cur; int idx = e;
    #pragma unroll
    for (int d = 16; d >= 1; d >>= 1) {
      float v2 = __shfl_xor(v, d, 32);
      int   i2 = __shfl_xor(idx, d, 32);
      if (v2 > v || (v2 == v && i2 < idx)) { v = v2; idx = i2; }
    }
    wv[it] = v; wi[it] = idx;
    if (e == idx) cur = -1e30f;
  }
  if (e == 0) {
    const float s4 = wv[0] + wv[1] + wv[2] + wv[3];
    #pragma unroll
    for (int k2 = 0; k2 < TOPK; ++k2) {
      topi[t * TOPK + k2] = wi[k2];
      topw[t * TOPK + k2] = wv[k2] / s4;
      atomicAdd(&counts[wi[k2]], 1);
    }
  }
}

__global__ void scan_offsets(const int* __restrict__ counts, int* __restrict__ offsets) {
  if (threadIdx.x == 0) {
    int a = 0;
    for (int e = 0; e < NE; ++e) { offsets[e] = a; a += counts[e]; }
    offsets[NE] = a;
  }
}

__global__ __launch_bounds__(256)
void fill_perm(const int* __restrict__ topi, const int* __restrict__ offsets,
               int* __restrict__ fill, int* __restrict__ perm, int* __restrict__ inv) {
  const int s = blockIdx.x * 256 + threadIdx.x;
  const int e = topi[s];
  const int pos = atomicAdd(&fill[e], 1);
  perm[offsets[e] + pos] = s;
  inv[s] = offsets[e] + pos;
}

// ============ p2 head: gather 4 ybuf rows, combine, relu, GEMV, tanh; std ==============
__global__ __launch_bounds__(256)
void p2_head(const u16* __restrict__ ybuf, const int* __restrict__ inv,
             const float* __restrict__ topw, const float* __restrict__ w,
             const float* __restrict__ b, const float* __restrict__ stdp,
             float* __restrict__ outp) {
  const int t = (blockIdx.x * 256 + threadIdx.x) >> 6;
  const int lane = threadIdx.x & 63;
  if (t >= T_DIM) return;
  const int p0 = inv[t * 4 + 0], p1 = inv[t * 4 + 1];
  const int p2 = inv[t * 4 + 2], p3 = inv[t * 4 + 3];
  const float w0 = topw[t * 4 + 0], w1 = topw[t * 4 + 1];
  const float w2 = topw[t * 4 + 2], w3 = topw[t * 4 + 3];
  const u16* y0 = ybuf + (size_t)p0 * HID_D;
  const u16* y1 = ybuf + (size_t)p1 * HID_D;
  const u16* y2 = ybuf + (size_t)p2 * HID_D;
  const u16* y3 = ybuf + (size_t)p3 * HID_D;
  float a[ACT_D] = {};
  for (int k = lane; k < HID_D; k += 64) {
    float xv = w0 * bf2f(y0[k]) + w1 * bf2f(y1[k]) + w2 * bf2f(y2[k]) + w3 * bf2f(y3[k]);
    xv = fmaxf(xv, 0.f);
    const float* wr = w + (size_t)k * ACT_D;
    #pragma unroll
    for (int j = 0; j < ACT_D; ++j) a[j] = fmaf(xv, wr[j], a[j]);
  }
  #pragma unroll
  for (int j = 0; j < ACT_D; ++j) {
    float v = a[j];
    #pragma unroll
    for (int d = 32; d >= 1; d >>= 1) v += __shfl_xor(v, d, 64);
    a[j] = v;
  }
  if (lane == 0) {
    const float sv = stdp[0];
    #pragma unroll
    for (int j = 0; j < ACT_D; ++j) {
      outp[(size_t)t * ACT_D + j] = tanhf(a[j] + b[j]);
      outp[(size_t)T_DIM * ACT_D + (size_t)t * ACT_D + j] = sv;
    }
  }
}

__global__ void aux_kernel(const float* __restrict__ imp, const int* __restrict__ counts,
                           float* __restrict__ outp) {
  const int e = threadIdx.x;
  float v = 0.f;
  if (e < NE)
    v = (imp[e] / (float)T_DIM) * ((float)counts[e] / (float)(T_DIM * TOPK));
  #pragma unroll
  for (int d = 32; d >= 1; d >>= 1) v += __shfl_xor(v, d, 64);
  if (e == 0) outp[2 * T_DIM * ACT_D] = (float)NE * v;
}

extern "C" void kernel_launch(void* const* d_in, const int* in_sizes, int n_in,
                              void* d_out, int out_size, void* d_ws, size_t ws_size,
                              hipStream_t stream) {
  const float* obs     = (const float*)d_in[0];
  const float* stdp    = (const float*)d_in[1];
  const float* trunk_w = (const float*)d_in[2];
  const float* trunk_b = (const float*)d_in[3];
  const float* ln_g    = (const float*)d_in[4];
  const float* ln_b    = (const float*)d_in[5];
  const float* p1_w    = (const float*)d_in[6];
  const float* p1_b    = (const float*)d_in[7];
  const float* g1_w    = (const float*)d_in[8];
  const float* g1_b    = (const float*)d_in[9];
  const float* g2_w    = (const float*)d_in[10];
  const float* g2_b    = (const float*)d_in[11];
  const float* ew1     = (const float*)d_in[12];
  const float* eb1     = (const float*)d_in[13];
  const float* ew2     = (const float*)d_in[14];
  const float* eb2     = (const float*)d_in[15];
  const float* p2_w    = (const float*)d_in[16];
  const float* p2_b    = (const float*)d_in[17];
  float* out = (float*)d_out;

  // ---- workspace layout with lifetime overlays ----
  char* p = (char*)d_ws;
  // [A] 50.33 MB: obs3 -> (h3 25.17 | x3 25.17); h3 sub-reused after p1: hgP 16.78 + hbuf 8.39
  u16*   obs3 = (u16*)p;
  u16*   h3   = (u16*)p;
  float* hgP  = (float*)p;
  u16*   hbuf = (u16*)(p + 4 * (size_t)T_DIM * GATE_D * 4);
  u16*   x3   = (u16*)(p + 3 * (size_t)T_DIM * FEAT_D * 2);
  p += 3 * (size_t)T_DIM * REPR_D * 2;
  // [B] 12.58 MB: trunk_wT3 -> (p1_wT3 6.29 + g1_wT3 1.57)
  u16* trunk_wT3 = (u16*)p;
  u16* p1_wT3    = (u16*)p;
  u16* g1_wT3    = (u16*)(p + 3 * (size_t)FEAT_D * HID_D * 2);
  p += 3 * (size_t)REPR_D * FEAT_D * 2;
  // [C] 33.55 MB: trunk partials (2 planes) -> p1 partials (2 planes) -> ybuf (bf16)
  float* hpP  = (float*)p;
  float* p1P  = (float*)p;
  u16*   ybuf = (u16*)p;
  p += 2 * (size_t)T_DIM * FEAT_D * 4;
  u16* ew1T = (u16*)p; p += (size_t)NE * HID_D * MH_D * 2;   // 16.78 MB
  u16* ew2T = (u16*)p; p += (size_t)NE * HID_D * MH_D * 2;   // 16.78 MB
  float* topw    = (float*)p; p += (size_t)T_DIM * TOPK * 4;
  int*   topi    = (int*)p;   p += (size_t)T_DIM * TOPK * 4;
  int*   perm    = (int*)p;   p += (size_t)T_DIM * TOPK * 4;
  int*   inv     = (int*)p;   p += (size_t)T_DIM * TOPK * 4;
  float* imp     = (float*)p; p += 128;
  int*   counts  = (int*)p;   p += 128;
  int*   offsets = (int*)p;   p += 256;
  int*   fill    = (int*)p;   p += 128;

  hipMemsetAsync(imp, 0, 128, stream);
  hipMemsetAsync(counts, 0, 128, stream);
  hipMemsetAsync(fill, 0, 128, stream);

  // obs + trunk_w -> 3-plane splits
  cast3_k<<<(T_DIM * REPR_D) / 1024, 256, 0, stream>>>(obs, obs3, (size_t)T_DIM * REPR_D);
  transpose_cast3<<<dim3(FEAT_D / 32, REPR_D / 32), 256, 0, stream>>>(trunk_w, trunk_wT3, REPR_D, FEAT_D);

  // trunk: 2-way split-K partials
  gemm_bf16x3_sk<<<dim3(FEAT_D / 128, T_DIM / 128, 2), 256, 0, stream>>>(
      obs3, trunk_wT3, hpP, T_DIM, FEAT_D, REPR_D);
  // [B] reuse (trunk_wT3 dead after trunk GEMM)
  transpose_cast3<<<dim3(HID_D / 32, FEAT_D / 32), 256, 0, stream>>>(p1_w, p1_wT3, FEAT_D, HID_D);
  transpose_cast3<<<dim3(GATE_D / 32, HID_D / 32), 256, 0, stream>>>(g1_w, g1_wT3, HID_D, GATE_D);

  // LN + tanh (sums 2 partials + bias) -> h3 ([A] reuse: obs3 dead)
  ln_tanh3<<<T_DIM, 256, 0, stream>>>(hpP, trunk_b, h3, ln_g, ln_b);

  // p1: 2-way split-K partials ([C] reuse: hpP dead), then combine -> x3
  gemm_bf16x3_sk<<<dim3(HID_D / 128, T_DIM / 128, 2), 256, 0, stream>>>(
      h3, p1_wT3, p1P, T_DIM, HID_D, FEAT_D);
  combine2_relu_split3<<<(T_DIM * HID_D) / 1024, 256, 0, stream>>>(p1P, p1_b, x3);

  // gate1: 4-way split-K partials into hgP (h3 region dead after p1)
  gemm_bf16x3_sk<<<dim3(GATE_D / 128, T_DIM / 128, 4), 256, 0, stream>>>(
      x3, g1_wT3, hgP, T_DIM, GATE_D, HID_D);

  gate2_topk<<<T_DIM / 8, 256, 0, stream>>>(hgP, g1_b, g2_w, g2_b, imp, counts, topi, topw);
  scan_offsets<<<1, 64, 0, stream>>>(counts, offsets);
  fill_perm<<<(T_DIM * TOPK) / 256, 256, 0, stream>>>(topi, offsets, fill, perm, inv);

  // expert value path (bf16): x plane0 = bf16(x)
  transpose_cast<<<dim3(MH_D / 32, HID_D / 32, NE), 256, 0, stream>>>(ew1, ew1T, HID_D, MH_D);
  transpose_cast<<<dim3(HID_D / 32, MH_D / 32, NE), 256, 0, stream>>>(ew2, ew2T, MH_D, HID_D);
  expert_l1<<<dim3(MH_D / 128, 32, NE), 256, 0, stream>>>(
      x3, ew1T, eb1, perm, offsets, counts, hbuf);
  // ybuf overlays p1P (dead after combine)
  expert_l2<<<dim3(HID_D / 128, 32, NE), 256, 0, stream>>>(
      hbuf, ew2T, eb2, offsets, counts, ybuf);

  p2_head<<<T_DIM / 4, 256, 0, stream>>>(ybuf, inv, topw, p2_w, p2_b, stdp, out);
  aux_kernel<<<1, 64, 0, stream>>>(imp, counts, out);
}

// Round 6
// 487.611 us; speedup vs baseline: 2.1927x; 1.0477x over previous
//
#include <hip/hip_runtime.h>
#include <math.h>

#define T_DIM  4096
#define REPR_D 2048
#define FEAT_D 1024
#define HID_D  1024
#define GATE_D 256
#define MH_D   256
#define NE     32
#define TOPK   4
#define ACT_D  12
#define LN_EPS 1e-5f

typedef unsigned short u16;
typedef __attribute__((ext_vector_type(8))) _Float16 f16x8;
typedef __attribute__((ext_vector_type(4))) float f32x4;
typedef __attribute__((ext_vector_type(4))) unsigned short u16x4;

__device__ __forceinline__ u16 f2h_bits(float f) {
  _Float16 h = (_Float16)f;
  return __builtin_bit_cast(u16, h);
}
__device__ __forceinline__ float h2f(u16 v) {
  return (float)__builtin_bit_cast(_Float16, v);
}
// split v = h0 + h1*2^-11, h1 stored pre-scaled by 2^11 (avoids fp16 subnormals)
__device__ __forceinline__ void split2h(float v, u16* h0, u16* h1) {
  _Float16 a = (_Float16)v;
  float r = v - (float)a;
  *h0 = __builtin_bit_cast(u16, a);
  *h1 = f2h_bits(r * 2048.0f);
}

__device__ __forceinline__ void gload16(const u16* g, u16* l) {
  __builtin_amdgcn_global_load_lds(
      (const __attribute__((address_space(1))) unsigned int*)g,
      (__attribute__((address_space(3))) unsigned int*)l, 16, 0, 0);
}

// ============ fp16x2 f32-emulated MFMA GEMM, split-K partials, XCD-chunk swizzle ========
// A: 2 fp16 planes [M][K] (plane1 pre-scaled 2^11), Bt: 2 planes [N][K] (same).
// acc1 = A0B0 ; acc2 = A0B1s + A1sB0 ; result = acc1 + acc2 * 2^-11.
// Error ~2^-22 relative (f32-grade). 128x128 tile, BK=32, 4 waves, 48 MFMA/K-step.
__global__ __launch_bounds__(256)
void gemm_f16x2_sk(const u16* __restrict__ A, const u16* __restrict__ Bt,
                   float* __restrict__ Cp, int M, int N, int K) {
  __shared__ u16 lA[2][128 * 32];
  __shared__ u16 lB[2][128 * 32];
  const int tid = threadIdx.x;
  // bijective XCD-chunk swizzle (requires nwg % 8 == 0; all launches satisfy)
  const unsigned gx = gridDim.x, gy = gridDim.y;
  const unsigned lin = blockIdx.x + gx * (blockIdx.y + gy * blockIdx.z);
  const unsigned q = (gx * gy * gridDim.z) >> 3;
  const unsigned swz = (lin & 7) * q + (lin >> 3);
  const int bn = (swz % gx) * 128;
  const int bm = ((swz / gx) % gy) * 128;
  const int bz = swz / (gx * gy);
  const int ksl = K / gridDim.z;
  const int kbeg = bz * ksl, kend = kbeg + ksl;
  const int lane = tid & 63, wid = tid >> 6;
  const int wm = (wid >> 1) * 64, wn = (wid & 1) * 64;
  const size_t sA = (size_t)M * K, sB = (size_t)N * K;
  const u16* pa = A + (size_t)(bm + (tid >> 2)) * K + (tid & 3) * 8;
  const u16* pb = Bt + (size_t)(bn + (tid >> 2)) * K + (tid & 3) * 8;
  u16* la = &lA[0][0] + tid * 8;
  u16* lb = &lB[0][0] + tid * 8;
  f32x4 acc1[4][4] = {}, acc2[4][4] = {};
  for (int k0 = kbeg; k0 < kend; k0 += 32) {
    #pragma unroll
    for (int p = 0; p < 2; ++p) {
      gload16(pa + p * sA + k0, la + p * 4096);
      gload16(pa + p * sA + (size_t)64 * K + k0, la + p * 4096 + 2048);
      gload16(pb + p * sB + k0, lb + p * 4096);
      gload16(pb + p * sB + (size_t)64 * K + k0, lb + p * 4096 + 2048);
    }
    __syncthreads();
    f16x8 af0[4], af1[4], bq[4];
    #pragma unroll
    for (int m = 0; m < 4; ++m) {
      af0[m] = *(const f16x8*)&lA[0][(wm + m * 16 + (lane & 15)) * 32 + (lane >> 4) * 8];
      af1[m] = *(const f16x8*)&lA[1][(wm + m * 16 + (lane & 15)) * 32 + (lane >> 4) * 8];
    }
    #pragma unroll
    for (int n = 0; n < 4; ++n)
      bq[n] = *(const f16x8*)&lB[0][(wn + n * 16 + (lane & 15)) * 32 + (lane >> 4) * 8];
    #pragma unroll
    for (int m = 0; m < 4; ++m)
      #pragma unroll
      for (int n = 0; n < 4; ++n) {
        acc1[m][n] = __builtin_amdgcn_mfma_f32_16x16x32_f16(af0[m], bq[n], acc1[m][n], 0, 0, 0);
        acc2[m][n] = __builtin_amdgcn_mfma_f32_16x16x32_f16(af1[m], bq[n], acc2[m][n], 0, 0, 0);
      }
    #pragma unroll
    for (int n = 0; n < 4; ++n)
      bq[n] = *(const f16x8*)&lB[1][(wn + n * 16 + (lane & 15)) * 32 + (lane >> 4) * 8];
    #pragma unroll
    for (int m = 0; m < 4; ++m)
      #pragma unroll
      for (int n = 0; n < 4; ++n)
        acc2[m][n] = __builtin_amdgcn_mfma_f32_16x16x32_f16(af0[m], bq[n], acc2[m][n], 0, 0, 0);
    __syncthreads();
  }
  float* Co = Cp + (size_t)bz * M * N;
  #pragma unroll
  for (int n = 0; n < 4; ++n) {
    const int col = bn + wn + n * 16 + (lane & 15);
    #pragma unroll
    for (int m = 0; m < 4; ++m) {
      #pragma unroll
      for (int r = 0; r < 4; ++r) {
        const int row = bm + wm + m * 16 + (lane >> 4) * 4 + r;
        Co[(size_t)row * N + col] = acc1[m][n][r] + acc2[m][n][r] * (1.0f / 2048.0f);
      }
    }
  }
}

// ============ single-plane fp16 MFMA expert GEMMs ======================================
__global__ __launch_bounds__(256)
void expert_l1(const u16* __restrict__ x, const u16* __restrict__ ew1T,
               const float* __restrict__ eb1, const int* __restrict__ perm,
               const int* __restrict__ offsets, const int* __restrict__ counts,
               u16* __restrict__ hbuf) {
  const int e = blockIdx.z;
  const int cnt = counts[e];
  const int r0 = blockIdx.y * 128;
  if (r0 >= cnt) return;
  const int base = offsets[e];
  const int bn = blockIdx.x * 128;
  __shared__ u16 lA[128 * 32];
  __shared__ u16 lB[128 * 32];
  __shared__ int toksm[128];
  const int tid = threadIdx.x;
  if (tid < 128) toksm[tid] = (r0 + tid < cnt) ? (perm[base + r0 + tid] >> 2) : 0;
  __syncthreads();
  const int lane = tid & 63, wid = tid >> 6;
  const int wm = (wid >> 1) * 64, wn = (wid & 1) * 64;
  const u16* pa0 = x + (size_t)toksm[tid >> 2] * HID_D + (tid & 3) * 8;
  const u16* pa1 = x + (size_t)toksm[64 + (tid >> 2)] * HID_D + (tid & 3) * 8;
  const u16* pb0 = ew1T + (size_t)e * MH_D * HID_D + (size_t)(bn + (tid >> 2)) * HID_D + (tid & 3) * 8;
  const u16* pb1 = pb0 + (size_t)64 * HID_D;
  u16* la = lA + tid * 8;
  u16* lb = lB + tid * 8;
  f32x4 acc[4][4] = {};
  for (int k0 = 0; k0 < HID_D; k0 += 32) {
    gload16(pa0 + k0, la);
    gload16(pa1 + k0, la + 2048);
    gload16(pb0 + k0, lb);
    gload16(pb1 + k0, lb + 2048);
    __syncthreads();
    f16x8 af[4], bfr[4];
    #pragma unroll
    for (int m = 0; m < 4; ++m)
      af[m] = *(const f16x8*)&lA[(wm + m * 16 + (lane & 15)) * 32 + (lane >> 4) * 8];
    #pragma unroll
    for (int n = 0; n < 4; ++n)
      bfr[n] = *(const f16x8*)&lB[(wn + n * 16 + (lane & 15)) * 32 + (lane >> 4) * 8];
    #pragma unroll
    for (int m = 0; m < 4; ++m)
      #pragma unroll
      for (int n = 0; n < 4; ++n)
        acc[m][n] = __builtin_amdgcn_mfma_f32_16x16x32_f16(af[m], bfr[n], acc[m][n], 0, 0, 0);
    __syncthreads();
  }
  #pragma unroll
  for (int n = 0; n < 4; ++n) {
    const int col = bn + wn + n * 16 + (lane & 15);
    const float bz = eb1[e * MH_D + col];
    #pragma unroll
    for (int m = 0; m < 4; ++m) {
      #pragma unroll
      for (int r = 0; r < 4; ++r) {
        const int rl = wm + m * 16 + (lane >> 4) * 4 + r;
        if (r0 + rl < cnt) {
          const float v = fmaxf(acc[m][n][r] + bz, 0.f);
          hbuf[(size_t)(base + r0 + rl) * MH_D + col] = f2h_bits(v);
        }
      }
    }
  }
}

// expert layer 2: writes per-slot rows (bias included, NO combine weight, NO relu)
__global__ __launch_bounds__(256)
void expert_l2(const u16* __restrict__ hbuf, const u16* __restrict__ ew2T,
               const float* __restrict__ eb2, const int* __restrict__ offsets,
               const int* __restrict__ counts, u16* __restrict__ ybuf) {
  const int e = blockIdx.z;
  const int cnt = counts[e];
  const int r0 = blockIdx.y * 128;
  if (r0 >= cnt) return;
  const int base = offsets[e];
  const int bn = blockIdx.x * 128;
  __shared__ u16 lA[128 * 32];
  __shared__ u16 lB[128 * 32];
  const int tid = threadIdx.x;
  const int lane = tid & 63, wid = tid >> 6;
  const int wm = (wid >> 1) * 64, wn = (wid & 1) * 64;
  const int ra = (r0 + (tid >> 2) < cnt) ? r0 + (tid >> 2) : cnt - 1;
  const int rb = (r0 + 64 + (tid >> 2) < cnt) ? r0 + 64 + (tid >> 2) : cnt - 1;
  const u16* pa0 = hbuf + (size_t)(base + ra) * MH_D + (tid & 3) * 8;
  const u16* pa1 = hbuf + (size_t)(base + rb) * MH_D + (tid & 3) * 8;
  const u16* pb0 = ew2T + (size_t)e * HID_D * MH_D + (size_t)(bn + (tid >> 2)) * MH_D + (tid & 3) * 8;
  const u16* pb1 = pb0 + (size_t)64 * MH_D;
  u16* la = lA + tid * 8;
  u16* lb = lB + tid * 8;
  f32x4 acc[4][4] = {};
  for (int k0 = 0; k0 < MH_D; k0 += 32) {
    gload16(pa0 + k0, la);
    gload16(pa1 + k0, la + 2048);
    gload16(pb0 + k0, lb);
    gload16(pb1 + k0, lb + 2048);
    __syncthreads();
    f16x8 af[4], bfr[4];
    #pragma unroll
    for (int m = 0; m < 4; ++m)
      af[m] = *(const f16x8*)&lA[(wm + m * 16 + (lane & 15)) * 32 + (lane >> 4) * 8];
    #pragma unroll
    for (int n = 0; n < 4; ++n)
      bfr[n] = *(const f16x8*)&lB[(wn + n * 16 + (lane & 15)) * 32 + (lane >> 4) * 8];
    #pragma unroll
    for (int m = 0; m < 4; ++m)
      #pragma unroll
      for (int n = 0; n < 4; ++n)
        acc[m][n] = __builtin_amdgcn_mfma_f32_16x16x32_f16(af[m], bfr[n], acc[m][n], 0, 0, 0);
    __syncthreads();
  }
  #pragma unroll
  for (int n = 0; n < 4; ++n) {
    const int col = bn + wn + n * 16 + (lane & 15);
    const float bz = eb2[e * HID_D + col];
    #pragma unroll
    for (int m = 0; m < 4; ++m) {
      #pragma unroll
      for (int r = 0; r < 4; ++r) {
        const int rl = wm + m * 16 + (lane >> 4) * 4 + r;
        if (r0 + rl < cnt)
          ybuf[(size_t)(base + r0 + rl) * HID_D + col] = f2h_bits(acc[m][n][r] + bz);
      }
    }
  }
}

// ============ cast / transpose / split helpers ==========================================
__global__ __launch_bounds__(256)
void cast2h_k(const float* __restrict__ in, u16* __restrict__ out, size_t total) {
  const size_t i = ((size_t)blockIdx.x * 256 + threadIdx.x) * 4;
  const float4 v = *(const float4*)(in + i);
  const float vv[4] = {v.x, v.y, v.z, v.w};
  u16x4 o0, o1;
  #pragma unroll
  for (int j = 0; j < 4; ++j) {
    u16 a, b;
    split2h(vv[j], &a, &b);
    o0[j] = a; o1[j] = b;
  }
  *(u16x4*)(out + i) = o0;
  *(u16x4*)(out + total + i) = o1;
}

// in: f32 [K][N], out: 2 fp16 planes [N][K]
__global__ __launch_bounds__(256)
void transpose_cast2h(const float* __restrict__ in, u16* __restrict__ out, int K, int N) {
  __shared__ float t[32][33];
  const int bn = blockIdx.x * 32, bk = blockIdx.y * 32;
  const int tx = threadIdx.x & 31, ty = threadIdx.x >> 5;
  const size_t NK = (size_t)N * K;
  #pragma unroll
  for (int i = 0; i < 32; i += 8) t[ty + i][tx] = in[(size_t)(bk + ty + i) * N + bn + tx];
  __syncthreads();
  #pragma unroll
  for (int i = 0; i < 32; i += 8) {
    const size_t idx = (size_t)(bn + ty + i) * K + bk + tx;
    u16 h0, h1;
    split2h(t[tx][ty + i], &h0, &h1);
    out[idx] = h0; out[idx + NK] = h1;
  }
}

// single-plane fp16 transpose-cast (expert weights)
__global__ __launch_bounds__(256)
void transpose_casth(const float* __restrict__ in, u16* __restrict__ out, int K, int N) {
  const size_t off = (size_t)blockIdx.z * K * N;
  in += off; out += off;
  __shared__ float t[32][33];
  const int bn = blockIdx.x * 32, bk = blockIdx.y * 32;
  const int tx = threadIdx.x & 31, ty = threadIdx.x >> 5;
  #pragma unroll
  for (int i = 0; i < 32; i += 8) t[ty + i][tx] = in[(size_t)(bk + ty + i) * N + bn + tx];
  __syncthreads();
  #pragma unroll
  for (int i = 0; i < 32; i += 8) out[(size_t)(bn + ty + i) * K + bk + tx] = f2h_bits(t[tx][ty + i]);
}

// ============ LN + tanh: sums 2 trunk partials + bias -> 2 fp16 planes ==================
__global__ __launch_bounds__(256)
void ln_tanh2h(const float* __restrict__ hp, const float* __restrict__ tb,
               u16* __restrict__ outp, const float* __restrict__ g,
               const float* __restrict__ b) {
  const int row = blockIdx.x, tid = threadIdx.x;
  const size_t MN = (size_t)T_DIM * FEAT_D;
  const float4 va = ((const float4*)(hp + (size_t)row * FEAT_D))[tid];
  const float4 vb = ((const float4*)(hp + MN + (size_t)row * FEAT_D))[tid];
  const float4 vt = ((const float4*)tb)[tid];
  float4 v;
  v.x = va.x + vb.x + vt.x; v.y = va.y + vb.y + vt.y;
  v.z = va.z + vb.z + vt.z; v.w = va.w + vb.w + vt.w;
  float s = v.x + v.y + v.z + v.w;
  float ss = v.x * v.x + v.y * v.y + v.z * v.z + v.w * v.w;
  #pragma unroll
  for (int d = 32; d >= 1; d >>= 1) { s += __shfl_xor(s, d, 64); ss += __shfl_xor(ss, d, 64); }
  __shared__ float red[2][4];
  const int w = tid >> 6;
  if ((tid & 63) == 0) { red[0][w] = s; red[1][w] = ss; }
  __syncthreads();
  s  = red[0][0] + red[0][1] + red[0][2] + red[0][3];
  ss = red[1][0] + red[1][1] + red[1][2] + red[1][3];
  const float m = s * (1.f / FEAT_D);
  const float inv = rsqrtf(ss * (1.f / FEAT_D) - m * m + LN_EPS);
  const float4 gg = ((const float4*)g)[tid];
  const float4 bb = ((const float4*)b)[tid];
  const float tv[4] = {tanhf((v.x - m) * inv * gg.x + bb.x),
                       tanhf((v.y - m) * inv * gg.y + bb.y),
                       tanhf((v.z - m) * inv * gg.z + bb.z),
                       tanhf((v.w - m) * inv * gg.w + bb.w)};
  u16x4 o0, o1;
  #pragma unroll
  for (int j = 0; j < 4; ++j) {
    u16 a, c;
    split2h(tv[j], &a, &c);
    o0[j] = a; o1[j] = c;
  }
  ((u16x4*)(outp + (size_t)row * FEAT_D))[tid] = o0;
  ((u16x4*)(outp + MN + (size_t)row * FEAT_D))[tid] = o1;
}

// ============ p1 combiner: sum 2 partials + bias, relu, split2 ==========================
__global__ __launch_bounds__(256)
void combine2_relu_split2h(const float* __restrict__ P, const float* __restrict__ bias,
                           u16* __restrict__ out2) {
  const size_t MN = (size_t)T_DIM * HID_D;
  const size_t i = ((size_t)blockIdx.x * 256 + threadIdx.x) * 4;
  const float4 a = *(const float4*)(P + i);
  const float4 b = *(const float4*)(P + MN + i);
  const float4 bz = *(const float4*)(bias + (i & (HID_D - 1)));
  const float vv[4] = {fmaxf(a.x + b.x + bz.x, 0.f), fmaxf(a.y + b.y + bz.y, 0.f),
                       fmaxf(a.z + b.z + bz.z, 0.f), fmaxf(a.w + b.w + bz.w, 0.f)};
  u16x4 o0, o1;
  #pragma unroll
  for (int j = 0; j < 4; ++j) {
    u16 h0, h1;
    split2h(vv[j], &h0, &h1);
    o0[j] = h0; o1[j] = h1;
  }
  *(u16x4*)(out2 + i) = o0;
  *(u16x4*)(out2 + MN + i) = o1;
}

// ============ gate2: sums 4 gate1 partials + bias + relu, softmax, top-4, aux ==========
__global__ __launch_bounds__(256)
void gate2_topk(const float* __restrict__ hgP, const float* __restrict__ g1b,
                const float* __restrict__ g2w, const float* __restrict__ g2b,
                float* __restrict__ imp, int* __restrict__ counts,
                int* __restrict__ topi, float* __restrict__ topw) {
  __shared__ float wsm[GATE_D][NE];
  __shared__ float rows[8][GATE_D];
  __shared__ float pacc[8][NE];
  const int tid = threadIdx.x;
  const int t0 = blockIdx.x * 8;
  const size_t TG = (size_t)T_DIM * GATE_D;
  for (int i = tid; i < GATE_D * NE; i += 256) wsm[i / NE][i % NE] = g2w[i];
  for (int i = tid; i < 8 * GATE_D; i += 256) {
    const int r = i / GATE_D, c = i % GATE_D;
    const size_t idx = (size_t)(t0 + r) * GATE_D + c;
    const float v = hgP[idx] + hgP[TG + idx] + hgP[2 * TG + idx] + hgP[3 * TG + idx] + g1b[c];
    rows[r][c] = fmaxf(v, 0.f);
  }
  __syncthreads();
  const int tl = tid >> 5;
  const int e  = tid & 31;
  const int t  = t0 + tl;
  float logit = g2b[e];
  for (int k = 0; k < GATE_D; ++k) logit = fmaf(rows[tl][k], wsm[k][e], logit);
  float m = logit;
  #pragma unroll
  for (int d = 16; d >= 1; d >>= 1) m = fmaxf(m, __shfl_xor(m, d, 32));
  const float p = expf(logit - m);
  float ssum = p;
  #pragma unroll
  for (int d = 16; d >= 1; d >>= 1) ssum += __shfl_xor(ssum, d, 32);
  const float prob = p / ssum;
  pacc[tl][e] = prob;
  __syncthreads();
  if (tl == 0) {
    float a = 0.f;
    #pragma unroll
    for (int q = 0; q < 8; ++q) a += pacc[q][e];
    atomicAdd(&imp[e], a);
  }
  float cur = prob;
  float wv[TOPK]; int wi[TOPK];
  #pragma unroll
  for (int it = 0; it < TOPK; ++it) {
    float v = cur; int idx = e;
    #pragma unroll
    for (int d = 16; d >= 1; d >>= 1) {
      float v2 = __shfl_xor(v, d, 32);
      int   i2 = __shfl_xor(idx, d, 32);
      if (v2 > v || (v2 == v && i2 < idx)) { v = v2; idx = i2; }
    }
    wv[it] = v; wi[it] = idx;
    if (e == idx) cur = -1e30f;
  }
  if (e == 0) {
    const float s4 = wv[0] + wv[1] + wv[2] + wv[3];
    #pragma unroll
    for (int k2 = 0; k2 < TOPK; ++k2) {
      topi[t * TOPK + k2] = wi[k2];
      topw[t * TOPK + k2] = wv[k2] / s4;
      atomicAdd(&counts[wi[k2]], 1);
    }
  }
}

__global__ void scan_offsets(const int* __restrict__ counts, int* __restrict__ offsets) {
  if (threadIdx.x == 0) {
    int a = 0;
    for (int e = 0; e < NE; ++e) { offsets[e] = a; a += counts[e]; }
    offsets[NE] = a;
  }
}

__global__ __launch_bounds__(256)
void fill_perm(const int* __restrict__ topi, const int* __restrict__ offsets,
               int* __restrict__ fill, int* __restrict__ perm, int* __restrict__ inv) {
  const int s = blockIdx.x * 256 + threadIdx.x;
  const int e = topi[s];
  const int pos = atomicAdd(&fill[e], 1);
  perm[offsets[e] + pos] = s;
  inv[s] = offsets[e] + pos;
}

// ============ p2 head: gather 4 ybuf rows, combine, relu, GEMV, tanh; std ==============
__global__ __launch_bounds__(256)
void p2_head(const u16* __restrict__ ybuf, const int* __restrict__ inv,
             const float* __restrict__ topw, const float* __restrict__ w,
             const float* __restrict__ b, const float* __restrict__ stdp,
             float* __restrict__ outp) {
  const int t = (blockIdx.x * 256 + threadIdx.x) >> 6;
  const int lane = threadIdx.x & 63;
  if (t >= T_DIM) return;
  const int p0 = inv[t * 4 + 0], p1 = inv[t * 4 + 1];
  const int p2 = inv[t * 4 + 2], p3 = inv[t * 4 + 3];
  const float w0 = topw[t * 4 + 0], w1 = topw[t * 4 + 1];
  const float w2 = topw[t * 4 + 2], w3 = topw[t * 4 + 3];
  const u16* y0 = ybuf + (size_t)p0 * HID_D;
  const u16* y1 = ybuf + (size_t)p1 * HID_D;
  const u16* y2 = ybuf + (size_t)p2 * HID_D;
  const u16* y3 = ybuf + (size_t)p3 * HID_D;
  float a[ACT_D] = {};
  for (int k = lane; k < HID_D; k += 64) {
    float xv = w0 * h2f(y0[k]) + w1 * h2f(y1[k]) + w2 * h2f(y2[k]) + w3 * h2f(y3[k]);
    xv = fmaxf(xv, 0.f);
    const float* wr = w + (size_t)k * ACT_D;
    #pragma unroll
    for (int j = 0; j < ACT_D; ++j) a[j] = fmaf(xv, wr[j], a[j]);
  }
  #pragma unroll
  for (int j = 0; j < ACT_D; ++j) {
    float v = a[j];
    #pragma unroll
    for (int d = 32; d >= 1; d >>= 1) v += __shfl_xor(v, d, 64);
    a[j] = v;
  }
  if (lane == 0) {
    const float sv = stdp[0];
    #pragma unroll
    for (int j = 0; j < ACT_D; ++j) {
      outp[(size_t)t * ACT_D + j] = tanhf(a[j] + b[j]);
      outp[(size_t)T_DIM * ACT_D + (size_t)t * ACT_D + j] = sv;
    }
  }
}

__global__ void aux_kernel(const float* __restrict__ imp, const int* __restrict__ counts,
                           float* __restrict__ outp) {
  const int e = threadIdx.x;
  float v = 0.f;
  if (e < NE)
    v = (imp[e] / (float)T_DIM) * ((float)counts[e] / (float)(T_DIM * TOPK));
  #pragma unroll
  for (int d = 32; d >= 1; d >>= 1) v += __shfl_xor(v, d, 64);
  if (e == 0) outp[2 * T_DIM * ACT_D] = (float)NE * v;
}

extern "C" void kernel_launch(void* const* d_in, const int* in_sizes, int n_in,
                              void* d_out, int out_size, void* d_ws, size_t ws_size,
                              hipStream_t stream) {
  const float* obs     = (const float*)d_in[0];
  const float* stdp    = (const float*)d_in[1];
  const float* trunk_w = (const float*)d_in[2];
  const float* trunk_b = (const float*)d_in[3];
  const float* ln_g    = (const float*)d_in[4];
  const float* ln_b    = (const float*)d_in[5];
  const float* p1_w    = (const float*)d_in[6];
  const float* p1_b    = (const float*)d_in[7];
  const float* g1_w    = (const float*)d_in[8];
  const float* g1_b    = (const float*)d_in[9];
  const float* g2_w    = (const float*)d_in[10];
  const float* g2_b    = (const float*)d_in[11];
  const float* ew1     = (const float*)d_in[12];
  const float* eb1     = (const float*)d_in[13];
  const float* ew2     = (const float*)d_in[14];
  const float* eb2     = (const float*)d_in[15];
  const float* p2_w    = (const float*)d_in[16];
  const float* p2_b    = (const float*)d_in[17];
  float* out = (float*)d_out;

  // ---- workspace layout with lifetime overlays ----
  char* p = (char*)d_ws;
  // [A] 33.55 MB: obs2 -> {h2 16.78 | x2 16.78}; h2 -> hgP (4xTxGATE f32) after p1
  u16*   obs2 = (u16*)p;
  u16*   h2   = (u16*)p;
  float* hgP  = (float*)p;
  u16*   x2   = (u16*)(p + 2 * (size_t)T_DIM * FEAT_D * 2);
  p += 2 * (size_t)T_DIM * REPR_D * 2;
  // [B] 8.39 MB: trunk_wT2 -> {p1_wT2 4.19 + g1_wT2 1.05} -> hbuf 8.39
  u16* trunk_wT2 = (u16*)p;
  u16* p1_wT2    = (u16*)p;
  u16* g1_wT2    = (u16*)(p + 2 * (size_t)FEAT_D * HID_D * 2);
  u16* hbuf      = (u16*)p;
  p += 2 * (size_t)REPR_D * FEAT_D * 2;
  // [C] 33.55 MB: trunk partials (2 f32 planes) -> p1 partials -> ybuf (fp16, 16384x1024)
  float* hpP  = (float*)p;
  float* p1P  = (float*)p;
  u16*   ybuf = (u16*)p;
  p += 2 * (size_t)T_DIM * FEAT_D * 4;
  u16* ew1T = (u16*)p; p += (size_t)NE * HID_D * MH_D * 2;   // 16.78 MB
  u16* ew2T = (u16*)p; p += (size_t)NE * HID_D * MH_D * 2;   // 16.78 MB
  float* topw    = (float*)p; p += (size_t)T_DIM * TOPK * 4;
  int*   topi    = (int*)p;   p += (size_t)T_DIM * TOPK * 4;
  int*   perm    = (int*)p;   p += (size_t)T_DIM * TOPK * 4;
  int*   inv     = (int*)p;   p += (size_t)T_DIM * TOPK * 4;
  float* imp     = (float*)p; p += 128;
  int*   counts  = (int*)p;   p += 128;
  int*   offsets = (int*)p;   p += 256;
  int*   fill    = (int*)p;   p += 128;

  hipMemsetAsync(imp, 0, 128, stream);
  hipMemsetAsync(counts, 0, 128, stream);
  hipMemsetAsync(fill, 0, 128, stream);

  // obs + trunk_w -> 2-plane fp16 splits
  cast2h_k<<<(T_DIM * REPR_D) / 1024, 256, 0, stream>>>(obs, obs2, (size_t)T_DIM * REPR_D);
  transpose_cast2h<<<dim3(FEAT_D / 32, REPR_D / 32), 256, 0, stream>>>(trunk_w, trunk_wT2, REPR_D, FEAT_D);

  // trunk: 2-way split-K partials (512 blocks, XCD-chunked)
  gemm_f16x2_sk<<<dim3(FEAT_D / 128, T_DIM / 128, 2), 256, 0, stream>>>(
      obs2, trunk_wT2, hpP, T_DIM, FEAT_D, REPR_D);
  // [B] reuse (trunk_wT2 dead)
  transpose_cast2h<<<dim3(HID_D / 32, FEAT_D / 32), 256, 0, stream>>>(p1_w, p1_wT2, FEAT_D, HID_D);
  transpose_cast2h<<<dim3(GATE_D / 32, HID_D / 32), 256, 0, stream>>>(g1_w, g1_wT2, HID_D, GATE_D);

  // LN + tanh (sums 2 partials + bias) -> h2 ([A] reuse: obs2 dead)
  ln_tanh2h<<<T_DIM, 256, 0, stream>>>(hpP, trunk_b, h2, ln_g, ln_b);

  // p1: 2-way split-K partials ([C] reuse: hpP dead), then combine -> x2
  gemm_f16x2_sk<<<dim3(HID_D / 128, T_DIM / 128, 2), 256, 0, stream>>>(
      h2, p1_wT2, p1P, T_DIM, HID_D, FEAT_D);
  combine2_relu_split2h<<<(T_DIM * HID_D) / 1024, 256, 0, stream>>>(p1P, p1_b, x2);

  // gate1: 4-way split-K partials into hgP (h2 dead after p1)
  gemm_f16x2_sk<<<dim3(GATE_D / 128, T_DIM / 128, 4), 256, 0, stream>>>(
      x2, g1_wT2, hgP, T_DIM, GATE_D, HID_D);

  gate2_topk<<<T_DIM / 8, 256, 0, stream>>>(hgP, g1_b, g2_w, g2_b, imp, counts, topi, topw);
  scan_offsets<<<1, 64, 0, stream>>>(counts, offsets);
  fill_perm<<<(T_DIM * TOPK) / 256, 256, 0, stream>>>(topi, offsets, fill, perm, inv);

  // expert value path (fp16, plane0 of x2), weights fp16
  transpose_casth<<<dim3(MH_D / 32, HID_D / 32, NE), 256, 0, stream>>>(ew1, ew1T, HID_D, MH_D);
  transpose_casth<<<dim3(HID_D / 32, MH_D / 32, NE), 256, 0, stream>>>(ew2, ew2T, MH_D, HID_D);
  expert_l1<<<dim3(MH_D / 128, 32, NE), 256, 0, stream>>>(
      x2, ew1T, eb1, perm, offsets, counts, hbuf);
  // ybuf overlays p1P (dead after combine)
  expert_l2<<<dim3(HID_D / 128, 32, NE), 256, 0, stream>>>(
      hbuf, ew2T, eb2, offsets, counts, ybuf);

  p2_head<<<T_DIM / 4, 256, 0, stream>>>(ybuf, inv, topw, p2_w, p2_b, stdp, out);
  aux_kernel<<<1, 64, 0, stream>>>(imp, counts, out);
}

// Round 7
// 453.751 us; speedup vs baseline: 2.3564x; 1.0746x over previous
//
#include <hip/hip_runtime.h>
#include <math.h>

#define T_DIM  4096
#define REPR_D 2048
#define FEAT_D 1024
#define HID_D  1024
#define GATE_D 256
#define MH_D   256
#define NE     32
#define TOPK   4
#define ACT_D  12
#define LN_EPS 1e-5f

typedef unsigned short u16;
typedef __attribute__((ext_vector_type(8))) _Float16 f16x8;
typedef __attribute__((ext_vector_type(4))) float f32x4;
typedef __attribute__((ext_vector_type(4))) unsigned short u16x4;

__device__ __forceinline__ u16 f2h_bits(float f) {
  _Float16 h = (_Float16)f;
  return __builtin_bit_cast(u16, h);
}
__device__ __forceinline__ float h2f(u16 v) {
  return (float)__builtin_bit_cast(_Float16, v);
}
// split v = h0 + h1*2^-11, h1 stored pre-scaled by 2^11 (avoids fp16 subnormals)
__device__ __forceinline__ void split2h(float v, u16* h0, u16* h1) {
  _Float16 a = (_Float16)v;
  float r = v - (float)a;
  *h0 = __builtin_bit_cast(u16, a);
  *h1 = f2h_bits(r * 2048.0f);
}

__device__ __forceinline__ void gload16(const u16* g, u16* l) {
  __builtin_amdgcn_global_load_lds(
      (const __attribute__((address_space(1))) unsigned int*)g,
      (__attribute__((address_space(3))) unsigned int*)l, 16, 0, 0);
}

// ============ fp16x2 f32-emulated MFMA GEMM, BK=64, slot-XOR LDS swizzle ================
// A: 2 fp16 planes [M][K] (plane1 pre-scaled 2^11), Bt: 2 planes [N][K] (same).
// acc1 = A0B0 ; acc2 = A0B1s + A1sB0 ; result = acc1 + acc2 * 2^-11.
// BK=64: 96 MFMA per barrier-pair. LDS rows are 128B so the 16B slot index is
// XOR-swizzled by (row&7) on BOTH the global source (pre-swizzle, rule #21) and
// the fragment read -> bank-balanced at the b128 floor. LDS stays write-linear.
__global__ __launch_bounds__(256)
void gemm_f16x2_sk(const u16* __restrict__ A, const u16* __restrict__ Bt,
                   float* __restrict__ Cp, int M, int N, int K) {
  __shared__ u16 lA[2][128 * 64];
  __shared__ u16 lB[2][128 * 64];
  const int tid = threadIdx.x;
  // bijective XCD-chunk swizzle (requires nwg % 8 == 0; all launches satisfy)
  const unsigned gx = gridDim.x, gy = gridDim.y;
  const unsigned lin = blockIdx.x + gx * (blockIdx.y + gy * blockIdx.z);
  const unsigned q = (gx * gy * gridDim.z) >> 3;
  const unsigned swz = (lin & 7) * q + (lin >> 3);
  const int bn = (swz % gx) * 128;
  const int bm = ((swz / gx) % gy) * 128;
  const int bz = swz / (gx * gy);
  const int ksl = K / gridDim.z;
  const int kbeg = bz * ksl, kend = kbeg + ksl;
  const int lane = tid & 63, wid = tid >> 6;
  const int wm = (wid >> 1) * 64, wn = (wid & 1) * 64;
  const size_t sA = (size_t)M * K, sB = (size_t)N * K;
  // staging: thread covers row (tid>>3)+32*s, slot' = (tid&7) ^ ((tid>>3)&7)
  const int srow = tid >> 3;
  const int coff = (((tid & 7) ^ (srow & 7)) * 8);
  const u16* pa = A + (size_t)(bm + srow) * K + coff;
  const u16* pb = Bt + (size_t)(bn + srow) * K + coff;
  u16* la = &lA[0][0] + tid * 8;
  u16* lb = &lB[0][0] + tid * 8;
  // fragment read indices
  const int fr = lane & 15;          // row within 16-row fragment
  const int sx = lane >> 4;          // k-slot base (0..3)
  const int rx = lane & 7;           // read-side XOR
  f32x4 acc1[4][4] = {}, acc2[4][4] = {};
  for (int k0 = kbeg; k0 < kend; k0 += 64) {
    #pragma unroll
    for (int p = 0; p < 2; ++p)
      #pragma unroll
      for (int s = 0; s < 4; ++s) {
        gload16(pa + p * sA + (size_t)(s * 32) * K + k0, la + p * 8192 + s * 2048);
        gload16(pb + p * sB + (size_t)(s * 32) * K + k0, lb + p * 8192 + s * 2048);
      }
    __syncthreads();
    #pragma unroll
    for (int kh = 0; kh < 2; ++kh) {
      const int sa = (((kh << 2) | sx) ^ rx) * 8;
      f16x8 af0[4], af1[4], bq[4];
      #pragma unroll
      for (int m = 0; m < 4; ++m) {
        af0[m] = *(const f16x8*)&lA[0][(wm + m * 16 + fr) * 64 + sa];
        af1[m] = *(const f16x8*)&lA[1][(wm + m * 16 + fr) * 64 + sa];
      }
      #pragma unroll
      for (int n = 0; n < 4; ++n)
        bq[n] = *(const f16x8*)&lB[0][(wn + n * 16 + fr) * 64 + sa];
      #pragma unroll
      for (int m = 0; m < 4; ++m)
        #pragma unroll
        for (int n = 0; n < 4; ++n) {
          acc1[m][n] = __builtin_amdgcn_mfma_f32_16x16x32_f16(af0[m], bq[n], acc1[m][n], 0, 0, 0);
          acc2[m][n] = __builtin_amdgcn_mfma_f32_16x16x32_f16(af1[m], bq[n], acc2[m][n], 0, 0, 0);
        }
      #pragma unroll
      for (int n = 0; n < 4; ++n)
        bq[n] = *(const f16x8*)&lB[1][(wn + n * 16 + fr) * 64 + sa];
      #pragma unroll
      for (int m = 0; m < 4; ++m)
        #pragma unroll
        for (int n = 0; n < 4; ++n)
          acc2[m][n] = __builtin_amdgcn_mfma_f32_16x16x32_f16(af0[m], bq[n], acc2[m][n], 0, 0, 0);
    }
    __syncthreads();
  }
  float* Co = Cp + (size_t)bz * M * N;
  #pragma unroll
  for (int n = 0; n < 4; ++n) {
    const int col = bn + wn + n * 16 + (lane & 15);
    #pragma unroll
    for (int m = 0; m < 4; ++m) {
      #pragma unroll
      for (int r = 0; r < 4; ++r) {
        const int row = bm + wm + m * 16 + (lane >> 4) * 4 + r;
        Co[(size_t)row * N + col] = acc1[m][n][r] + acc2[m][n][r] * (1.0f / 2048.0f);
      }
    }
  }
}

// ============ single-plane fp16 MFMA expert GEMMs (BK=32, unchanged) ===================
__global__ __launch_bounds__(256)
void expert_l1(const u16* __restrict__ x, const u16* __restrict__ ew1T,
               const float* __restrict__ eb1, const int* __restrict__ perm,
               const int* __restrict__ offsets, const int* __restrict__ counts,
               u16* __restrict__ hbuf) {
  const int e = blockIdx.z;
  const int cnt = counts[e];
  const int r0 = blockIdx.y * 128;
  if (r0 >= cnt) return;
  const int base = offsets[e];
  const int bn = blockIdx.x * 128;
  __shared__ u16 lA[128 * 32];
  __shared__ u16 lB[128 * 32];
  __shared__ int toksm[128];
  const int tid = threadIdx.x;
  if (tid < 128) toksm[tid] = (r0 + tid < cnt) ? (perm[base + r0 + tid] >> 2) : 0;
  __syncthreads();
  const int lane = tid & 63, wid = tid >> 6;
  const int wm = (wid >> 1) * 64, wn = (wid & 1) * 64;
  const u16* pa0 = x + (size_t)toksm[tid >> 2] * HID_D + (tid & 3) * 8;
  const u16* pa1 = x + (size_t)toksm[64 + (tid >> 2)] * HID_D + (tid & 3) * 8;
  const u16* pb0 = ew1T + (size_t)e * MH_D * HID_D + (size_t)(bn + (tid >> 2)) * HID_D + (tid & 3) * 8;
  const u16* pb1 = pb0 + (size_t)64 * HID_D;
  u16* la = lA + tid * 8;
  u16* lb = lB + tid * 8;
  f32x4 acc[4][4] = {};
  for (int k0 = 0; k0 < HID_D; k0 += 32) {
    gload16(pa0 + k0, la);
    gload16(pa1 + k0, la + 2048);
    gload16(pb0 + k0, lb);
    gload16(pb1 + k0, lb + 2048);
    __syncthreads();
    f16x8 af[4], bfr[4];
    #pragma unroll
    for (int m = 0; m < 4; ++m)
      af[m] = *(const f16x8*)&lA[(wm + m * 16 + (lane & 15)) * 32 + (lane >> 4) * 8];
    #pragma unroll
    for (int n = 0; n < 4; ++n)
      bfr[n] = *(const f16x8*)&lB[(wn + n * 16 + (lane & 15)) * 32 + (lane >> 4) * 8];
    #pragma unroll
    for (int m = 0; m < 4; ++m)
      #pragma unroll
      for (int n = 0; n < 4; ++n)
        acc[m][n] = __builtin_amdgcn_mfma_f32_16x16x32_f16(af[m], bfr[n], acc[m][n], 0, 0, 0);
    __syncthreads();
  }
  #pragma unroll
  for (int n = 0; n < 4; ++n) {
    const int col = bn + wn + n * 16 + (lane & 15);
    const float bz = eb1[e * MH_D + col];
    #pragma unroll
    for (int m = 0; m < 4; ++m) {
      #pragma unroll
      for (int r = 0; r < 4; ++r) {
        const int rl = wm + m * 16 + (lane >> 4) * 4 + r;
        if (r0 + rl < cnt) {
          const float v = fmaxf(acc[m][n][r] + bz, 0.f);
          hbuf[(size_t)(base + r0 + rl) * MH_D + col] = f2h_bits(v);
        }
      }
    }
  }
}

// expert layer 2: writes per-slot rows (bias included, NO combine weight, NO relu)
__global__ __launch_bounds__(256)
void expert_l2(const u16* __restrict__ hbuf, const u16* __restrict__ ew2T,
               const float* __restrict__ eb2, const int* __restrict__ offsets,
               const int* __restrict__ counts, u16* __restrict__ ybuf) {
  const int e = blockIdx.z;
  const int cnt = counts[e];
  const int r0 = blockIdx.y * 128;
  if (r0 >= cnt) return;
  const int base = offsets[e];
  const int bn = blockIdx.x * 128;
  __shared__ u16 lA[128 * 32];
  __shared__ u16 lB[128 * 32];
  const int tid = threadIdx.x;
  const int lane = tid & 63, wid = tid >> 6;
  const int wm = (wid >> 1) * 64, wn = (wid & 1) * 64;
  const int ra = (r0 + (tid >> 2) < cnt) ? r0 + (tid >> 2) : cnt - 1;
  const int rb = (r0 + 64 + (tid >> 2) < cnt) ? r0 + 64 + (tid >> 2) : cnt - 1;
  const u16* pa0 = hbuf + (size_t)(base + ra) * MH_D + (tid & 3) * 8;
  const u16* pa1 = hbuf + (size_t)(base + rb) * MH_D + (tid & 3) * 8;
  const u16* pb0 = ew2T + (size_t)e * HID_D * MH_D + (size_t)(bn + (tid >> 2)) * MH_D + (tid & 3) * 8;
  const u16* pb1 = pb0 + (size_t)64 * MH_D;
  u16* la = lA + tid * 8;
  u16* lb = lB + tid * 8;
  f32x4 acc[4][4] = {};
  for (int k0 = 0; k0 < MH_D; k0 += 32) {
    gload16(pa0 + k0, la);
    gload16(pa1 + k0, la + 2048);
    gload16(pb0 + k0, lb);
    gload16(pb1 + k0, lb + 2048);
    __syncthreads();
    f16x8 af[4], bfr[4];
    #pragma unroll
    for (int m = 0; m < 4; ++m)
      af[m] = *(const f16x8*)&lA[(wm + m * 16 + (lane & 15)) * 32 + (lane >> 4) * 8];
    #pragma unroll
    for (int n = 0; n < 4; ++n)
      bfr[n] = *(const f16x8*)&lB[(wn + n * 16 + (lane & 15)) * 32 + (lane >> 4) * 8];
    #pragma unroll
    for (int m = 0; m < 4; ++m)
      #pragma unroll
      for (int n = 0; n < 4; ++n)
        acc[m][n] = __builtin_amdgcn_mfma_f32_16x16x32_f16(af[m], bfr[n], acc[m][n], 0, 0, 0);
    __syncthreads();
  }
  #pragma unroll
  for (int n = 0; n < 4; ++n) {
    const int col = bn + wn + n * 16 + (lane & 15);
    const float bz = eb2[e * HID_D + col];
    #pragma unroll
    for (int m = 0; m < 4; ++m) {
      #pragma unroll
      for (int r = 0; r < 4; ++r) {
        const int rl = wm + m * 16 + (lane >> 4) * 4 + r;
        if (r0 + rl < cnt)
          ybuf[(size_t)(base + r0 + rl) * HID_D + col] = f2h_bits(acc[m][n][r] + bz);
      }
    }
  }
}

// ============ cast / transpose / split helpers ==========================================
__global__ __launch_bounds__(256)
void cast2h_k(const float* __restrict__ in, u16* __restrict__ out, size_t total) {
  const size_t i = ((size_t)blockIdx.x * 256 + threadIdx.x) * 4;
  const float4 v = *(const float4*)(in + i);
  const float vv[4] = {v.x, v.y, v.z, v.w};
  u16x4 o0, o1;
  #pragma unroll
  for (int j = 0; j < 4; ++j) {
    u16 a, b;
    split2h(vv[j], &a, &b);
    o0[j] = a; o1[j] = b;
  }
  *(u16x4*)(out + i) = o0;
  *(u16x4*)(out + total + i) = o1;
}

// in: f32 [K][N], out: 2 fp16 planes [N][K]
__global__ __launch_bounds__(256)
void transpose_cast2h(const float* __restrict__ in, u16* __restrict__ out, int K, int N) {
  __shared__ float t[32][33];
  const int bn = blockIdx.x * 32, bk = blockIdx.y * 32;
  const int tx = threadIdx.x & 31, ty = threadIdx.x >> 5;
  const size_t NK = (size_t)N * K;
  #pragma unroll
  for (int i = 0; i < 32; i += 8) t[ty + i][tx] = in[(size_t)(bk + ty + i) * N + bn + tx];
  __syncthreads();
  #pragma unroll
  for (int i = 0; i < 32; i += 8) {
    const size_t idx = (size_t)(bn + ty + i) * K + bk + tx;
    u16 h0, h1;
    split2h(t[tx][ty + i], &h0, &h1);
    out[idx] = h0; out[idx + NK] = h1;
  }
}

// single-plane fp16 transpose-cast (expert weights)
__global__ __launch_bounds__(256)
void transpose_casth(const float* __restrict__ in, u16* __restrict__ out, int K, int N) {
  const size_t off = (size_t)blockIdx.z * K * N;
  in += off; out += off;
  __shared__ float t[32][33];
  const int bn = blockIdx.x * 32, bk = blockIdx.y * 32;
  const int tx = threadIdx.x & 31, ty = threadIdx.x >> 5;
  #pragma unroll
  for (int i = 0; i < 32; i += 8) t[ty + i][tx] = in[(size_t)(bk + ty + i) * N + bn + tx];
  __syncthreads();
  #pragma unroll
  for (int i = 0; i < 32; i += 8) out[(size_t)(bn + ty + i) * K + bk + tx] = f2h_bits(t[tx][ty + i]);
}

// ============ LN + tanh: sums 2 trunk partials + bias -> 2 fp16 planes ==================
__global__ __launch_bounds__(256)
void ln_tanh2h(const float* __restrict__ hp, const float* __restrict__ tb,
               u16* __restrict__ outp, const float* __restrict__ g,
               const float* __restrict__ b) {
  const int row = blockIdx.x, tid = threadIdx.x;
  const size_t MN = (size_t)T_DIM * FEAT_D;
  const float4 va = ((const float4*)(hp + (size_t)row * FEAT_D))[tid];
  const float4 vb = ((const float4*)(hp + MN + (size_t)row * FEAT_D))[tid];
  const float4 vt = ((const float4*)tb)[tid];
  float4 v;
  v.x = va.x + vb.x + vt.x; v.y = va.y + vb.y + vt.y;
  v.z = va.z + vb.z + vt.z; v.w = va.w + vb.w + vt.w;
  float s = v.x + v.y + v.z + v.w;
  float ss = v.x * v.x + v.y * v.y + v.z * v.z + v.w * v.w;
  #pragma unroll
  for (int d = 32; d >= 1; d >>= 1) { s += __shfl_xor(s, d, 64); ss += __shfl_xor(ss, d, 64); }
  __shared__ float red[2][4];
  const int w = tid >> 6;
  if ((tid & 63) == 0) { red[0][w] = s; red[1][w] = ss; }
  __syncthreads();
  s  = red[0][0] + red[0][1] + red[0][2] + red[0][3];
  ss = red[1][0] + red[1][1] + red[1][2] + red[1][3];
  const float m = s * (1.f / FEAT_D);
  const float inv = rsqrtf(ss * (1.f / FEAT_D) - m * m + LN_EPS);
  const float4 gg = ((const float4*)g)[tid];
  const float4 bb = ((const float4*)b)[tid];
  const float tv[4] = {tanhf((v.x - m) * inv * gg.x + bb.x),
                       tanhf((v.y - m) * inv * gg.y + bb.y),
                       tanhf((v.z - m) * inv * gg.z + bb.z),
                       tanhf((v.w - m) * inv * gg.w + bb.w)};
  u16x4 o0, o1;
  #pragma unroll
  for (int j = 0; j < 4; ++j) {
    u16 a, c;
    split2h(tv[j], &a, &c);
    o0[j] = a; o1[j] = c;
  }
  ((u16x4*)(outp + (size_t)row * FEAT_D))[tid] = o0;
  ((u16x4*)(outp + MN + (size_t)row * FEAT_D))[tid] = o1;
}

// ============ p1 combiner: sum 2 partials + bias, relu, split2 ==========================
__global__ __launch_bounds__(256)
void combine2_relu_split2h(const float* __restrict__ P, const float* __restrict__ bias,
                           u16* __restrict__ out2) {
  const size_t MN = (size_t)T_DIM * HID_D;
  const size_t i = ((size_t)blockIdx.x * 256 + threadIdx.x) * 4;
  const float4 a = *(const float4*)(P + i);
  const float4 b = *(const float4*)(P + MN + i);
  const float4 bz = *(const float4*)(bias + (i & (HID_D - 1)));
  const float vv[4] = {fmaxf(a.x + b.x + bz.x, 0.f), fmaxf(a.y + b.y + bz.y, 0.f),
                       fmaxf(a.z + b.z + bz.z, 0.f), fmaxf(a.w + b.w + bz.w, 0.f)};
  u16x4 o0, o1;
  #pragma unroll
  for (int j = 0; j < 4; ++j) {
    u16 h0, h1;
    split2h(vv[j], &h0, &h1);
    o0[j] = h0; o1[j] = h1;
  }
  *(u16x4*)(out2 + i) = o0;
  *(u16x4*)(out2 + MN + i) = o1;
}

// ============ gate2: sums 4 gate1 partials + bias + relu, softmax, top-4, aux ==========
__global__ __launch_bounds__(256)
void gate2_topk(const float* __restrict__ hgP, const float* __restrict__ g1b,
                const float* __restrict__ g2w, const float* __restrict__ g2b,
                float* __restrict__ imp, int* __restrict__ counts,
                int* __restrict__ topi, float* __restrict__ topw) {
  __shared__ float wsm[GATE_D][NE];
  __shared__ float rows[8][GATE_D];
  __shared__ float pacc[8][NE];
  const int tid = threadIdx.x;
  const int t0 = blockIdx.x * 8;
  const size_t TG = (size_t)T_DIM * GATE_D;
  for (int i = tid; i < GATE_D * NE; i += 256) wsm[i / NE][i % NE] = g2w[i];
  for (int i = tid; i < 8 * GATE_D; i += 256) {
    const int r = i / GATE_D, c = i % GATE_D;
    const size_t idx = (size_t)(t0 + r) * GATE_D + c;
    const float v = hgP[idx] + hgP[TG + idx] + hgP[2 * TG + idx] + hgP[3 * TG + idx] + g1b[c];
    rows[r][c] = fmaxf(v, 0.f);
  }
  __syncthreads();
  const int tl = tid >> 5;
  const int e  = tid & 31;
  const int t  = t0 + tl;
  float logit = g2b[e];
  for (int k = 0; k < GATE_D; ++k) logit = fmaf(rows[tl][k], wsm[k][e], logit);
  float m = logit;
  #pragma unroll
  for (int d = 16; d >= 1; d >>= 1) m = fmaxf(m, __shfl_xor(m, d, 32));
  const float p = expf(logit - m);
  float ssum = p;
  #pragma unroll
  for (int d = 16; d >= 1; d >>= 1) ssum += __shfl_xor(ssum, d, 32);
  const float prob = p / ssum;
  pacc[tl][e] = prob;
  __syncthreads();
  if (tl == 0) {
    float a = 0.f;
    #pragma unroll
    for (int q = 0; q < 8; ++q) a += pacc[q][e];
    atomicAdd(&imp[e], a);
  }
  float cur = prob;
  float wv[TOPK]; int wi[TOPK];
  #pragma unroll
  for (int it = 0; it < TOPK; ++it) {
    float v = cur; int idx = e;
    #pragma unroll
    for (int d = 16; d >= 1; d >>= 1) {
      float v2 = __shfl_xor(v, d, 32);
      int   i2 = __shfl_xor(idx, d, 32);
      if (v2 > v || (v2 == v && i2 < idx)) { v = v2; idx = i2; }
    }
    wv[it] = v; wi[it] = idx;
    if (e == idx) cur = -1e30f;
  }
  if (e == 0) {
    const float s4 = wv[0] + wv[1] + wv[2] + wv[3];
    #pragma unroll
    for (int k2 = 0; k2 < TOPK; ++k2) {
      topi[t * TOPK + k2] = wi[k2];
      topw[t * TOPK + k2] = wv[k2] / s4;
      atomicAdd(&counts[wi[k2]], 1);
    }
  }
}

__global__ void scan_offsets(const int* __restrict__ counts, int* __restrict__ offsets) {
  if (threadIdx.x == 0) {
    int a = 0;
    for (int e = 0; e < NE; ++e) { offsets[e] = a; a += counts[e]; }
    offsets[NE] = a;
  }
}

__global__ __launch_bounds__(256)
void fill_perm(const int* __restrict__ topi, const int* __restrict__ offsets,
               int* __restrict__ fill, int* __restrict__ perm, int* __restrict__ inv) {
  const int s = blockIdx.x * 256 + threadIdx.x;
  const int e = topi[s];
  const int pos = atomicAdd(&fill[e], 1);
  perm[offsets[e] + pos] = s;
  inv[s] = offsets[e] + pos;
}

// ============ p2 head: gather 4 ybuf rows, combine, relu, GEMV, tanh; std ==============
__global__ __launch_bounds__(256)
void p2_head(const u16* __restrict__ ybuf, const int* __restrict__ inv,
             const float* __restrict__ topw, const float* __restrict__ w,
             const float* __restrict__ b, const float* __restrict__ stdp,
             float* __restrict__ outp) {
  const int t = (blockIdx.x * 256 + threadIdx.x) >> 6;
  const int lane = threadIdx.x & 63;
  if (t >= T_DIM) return;
  const int p0 = inv[t * 4 + 0], p1 = inv[t * 4 + 1];
  const int p2 = inv[t * 4 + 2], p3 = inv[t * 4 + 3];
  const float w0 = topw[t * 4 + 0], w1 = topw[t * 4 + 1];
  const float w2 = topw[t * 4 + 2], w3 = topw[t * 4 + 3];
  const u16* y0 = ybuf + (size_t)p0 * HID_D;
  const u16* y1 = ybuf + (size_t)p1 * HID_D;
  const u16* y2 = ybuf + (size_t)p2 * HID_D;
  const u16* y3 = ybuf + (size_t)p3 * HID_D;
  float a[ACT_D] = {};
  for (int k = lane; k < HID_D; k += 64) {
    float xv = w0 * h2f(y0[k]) + w1 * h2f(y1[k]) + w2 * h2f(y2[k]) + w3 * h2f(y3[k]);
    xv = fmaxf(xv, 0.f);
    const float* wr = w + (size_t)k * ACT_D;
    #pragma unroll
    for (int j = 0; j < ACT_D; ++j) a[j] = fmaf(xv, wr[j], a[j]);
  }
  #pragma unroll
  for (int j = 0; j < ACT_D; ++j) {
    float v = a[j];
    #pragma unroll
    for (int d = 32; d >= 1; d >>= 1) v += __shfl_xor(v, d, 64);
    a[j] = v;
  }
  if (lane == 0) {
    const float sv = stdp[0];
    #pragma unroll
    for (int j = 0; j < ACT_D; ++j) {
      outp[(size_t)t * ACT_D + j] = tanhf(a[j] + b[j]);
      outp[(size_t)T_DIM * ACT_D + (size_t)t * ACT_D + j] = sv;
    }
  }
}

__global__ void aux_kernel(const float* __restrict__ imp, const int* __restrict__ counts,
                           float* __restrict__ outp) {
  const int e = threadIdx.x;
  float v = 0.f;
  if (e < NE)
    v = (imp[e] / (float)T_DIM) * ((float)counts[e] / (float)(T_DIM * TOPK));
  #pragma unroll
  for (int d = 32; d >= 1; d >>= 1) v += __shfl_xor(v, d, 64);
  if (e == 0) outp[2 * T_DIM * ACT_D] = (float)NE * v;
}

extern "C" void kernel_launch(void* const* d_in, const int* in_sizes, int n_in,
                              void* d_out, int out_size, void* d_ws, size_t ws_size,
                              hipStream_t stream) {
  const float* obs     = (const float*)d_in[0];
  const float* stdp    = (const float*)d_in[1];
  const float* trunk_w = (const float*)d_in[2];
  const float* trunk_b = (const float*)d_in[3];
  const float* ln_g    = (const float*)d_in[4];
  const float* ln_b    = (const float*)d_in[5];
  const float* p1_w    = (const float*)d_in[6];
  const float* p1_b    = (const float*)d_in[7];
  const float* g1_w    = (const float*)d_in[8];
  const float* g1_b    = (const float*)d_in[9];
  const float* g2_w    = (const float*)d_in[10];
  const float* g2_b    = (const float*)d_in[11];
  const float* ew1     = (const float*)d_in[12];
  const float* eb1     = (const float*)d_in[13];
  const float* ew2     = (const float*)d_in[14];
  const float* eb2     = (const float*)d_in[15];
  const float* p2_w    = (const float*)d_in[16];
  const float* p2_b    = (const float*)d_in[17];
  float* out = (float*)d_out;

  // ---- workspace layout with lifetime overlays ----
  char* p = (char*)d_ws;
  // [A] 33.55 MB: obs2 -> {h2 16.78 | x2 16.78}; h2 -> hgP (4xTxGATE f32) after p1
  u16*   obs2 = (u16*)p;
  u16*   h2   = (u16*)p;
  float* hgP  = (float*)p;
  u16*   x2   = (u16*)(p + 2 * (size_t)T_DIM * FEAT_D * 2);
  p += 2 * (size_t)T_DIM * REPR_D * 2;
  // [B] 8.39 MB: trunk_wT2 -> {p1_wT2 4.19 + g1_wT2 1.05} -> hbuf 8.39
  u16* trunk_wT2 = (u16*)p;
  u16* p1_wT2    = (u16*)p;
  u16* g1_wT2    = (u16*)(p + 2 * (size_t)FEAT_D * HID_D * 2);
  u16* hbuf      = (u16*)p;
  p += 2 * (size_t)REPR_D * FEAT_D * 2;
  // [C] 33.55 MB: trunk partials (2 f32 planes) -> p1 partials -> ybuf (fp16, 16384x1024)
  float* hpP  = (float*)p;
  float* p1P  = (float*)p;
  u16*   ybuf = (u16*)p;
  p += 2 * (size_t)T_DIM * FEAT_D * 4;
  u16* ew1T = (u16*)p; p += (size_t)NE * HID_D * MH_D * 2;   // 16.78 MB
  u16* ew2T = (u16*)p; p += (size_t)NE * HID_D * MH_D * 2;   // 16.78 MB
  float* topw    = (float*)p; p += (size_t)T_DIM * TOPK * 4;
  int*   topi    = (int*)p;   p += (size_t)T_DIM * TOPK * 4;
  int*   perm    = (int*)p;   p += (size_t)T_DIM * TOPK * 4;
  int*   inv     = (int*)p;   p += (size_t)T_DIM * TOPK * 4;
  float* imp     = (float*)p; p += 128;
  int*   counts  = (int*)p;   p += 128;
  int*   offsets = (int*)p;   p += 256;
  int*   fill    = (int*)p;   p += 128;

  hipMemsetAsync(imp, 0, 128, stream);
  hipMemsetAsync(counts, 0, 128, stream);
  hipMemsetAsync(fill, 0, 128, stream);

  // obs + trunk_w -> 2-plane fp16 splits
  cast2h_k<<<(T_DIM * REPR_D) / 1024, 256, 0, stream>>>(obs, obs2, (size_t)T_DIM * REPR_D);
  transpose_cast2h<<<dim3(FEAT_D / 32, REPR_D / 32), 256, 0, stream>>>(trunk_w, trunk_wT2, REPR_D, FEAT_D);

  // trunk: 2-way split-K partials (512 blocks, XCD-chunked)
  gemm_f16x2_sk<<<dim3(FEAT_D / 128, T_DIM / 128, 2), 256, 0, stream>>>(
      obs2, trunk_wT2, hpP, T_DIM, FEAT_D, REPR_D);
  // [B] reuse (trunk_wT2 dead)
  transpose_cast2h<<<dim3(HID_D / 32, FEAT_D / 32), 256, 0, stream>>>(p1_w, p1_wT2, FEAT_D, HID_D);
  transpose_cast2h<<<dim3(GATE_D / 32, HID_D / 32), 256, 0, stream>>>(g1_w, g1_wT2, HID_D, GATE_D);

  // LN + tanh (sums 2 partials + bias) -> h2 ([A] reuse: obs2 dead)
  ln_tanh2h<<<T_DIM, 256, 0, stream>>>(hpP, trunk_b, h2, ln_g, ln_b);

  // p1: 2-way split-K partials ([C] reuse: hpP dead), then combine -> x2
  gemm_f16x2_sk<<<dim3(HID_D / 128, T_DIM / 128, 2), 256, 0, stream>>>(
      h2, p1_wT2, p1P, T_DIM, HID_D, FEAT_D);
  combine2_relu_split2h<<<(T_DIM * HID_D) / 1024, 256, 0, stream>>>(p1P, p1_b, x2);

  // gate1: 4-way split-K partials into hgP (h2 dead after p1)
  gemm_f16x2_sk<<<dim3(GATE_D / 128, T_DIM / 128, 4), 256, 0, stream>>>(
      x2, g1_wT2, hgP, T_DIM, GATE_D, HID_D);

  gate2_topk<<<T_DIM / 8, 256, 0, stream>>>(hgP, g1_b, g2_w, g2_b, imp, counts, topi, topw);
  scan_offsets<<<1, 64, 0, stream>>>(counts, offsets);
  fill_perm<<<(T_DIM * TOPK) / 256, 256, 0, stream>>>(topi, offsets, fill, perm, inv);

  // expert value path (fp16, plane0 of x2), weights fp16
  transpose_casth<<<dim3(MH_D / 32, HID_D / 32, NE), 256, 0, stream>>>(ew1, ew1T, HID_D, MH_D);
  transpose_casth<<<dim3(HID_D / 32, MH_D / 32, NE), 256, 0, stream>>>(ew2, ew2T, MH_D, HID_D);
  expert_l1<<<dim3(MH_D / 128, 32, NE), 256, 0, stream>>>(
      x2, ew1T, eb1, perm, offsets, counts, hbuf);
  // ybuf overlays p1P (dead after combine)
  expert_l2<<<dim3(HID_D / 128, 32, NE), 256, 0, stream>>>(
      hbuf, ew2T, eb2, offsets, counts, ybuf);

  p2_head<<<T_DIM / 4, 256, 0, stream>>>(ybuf, inv, topw, p2_w, p2_b, stdp, out);
  aux_kernel<<<1, 64, 0, stream>>>(imp, counts, out);
}